// Round 9
// baseline (193.879 us; speedup 1.0000x reference)
//
#include <hip/hip_runtime.h>
#include <cmath>

static constexpr int B_  = 16;
static constexpr int N_  = 2048;
static constexpr int NT_ = 32768;
static constexpr int E_  = 524288;

// Workspace layout (float-element offsets) -- round-21 relayout:
static constexpr size_t OFF_HSC    = 0;          // NT_*64
static constexpr size_t OFF_SWS    = 6291456;    // specp[1024]
static constexpr size_t OFF_GSP    = 9437184;    // 128*64
static constexpr size_t OFF_GSP2   = 9445376;    // 128*64
// int region
static constexpr size_t OFF_IHIN   = 10043904;   // 262144 per-partition in-hists
static constexpr size_t OFF_IHOUT  = 10306048;   // 262144 per-partition out-hists
static constexpr size_t OFF_IROWS  = 10830336;   // 32772
static constexpr size_t OFF_IESRC  = 10895876;   // 524288
// round-21: 1024 tiles of 32 nodes
static constexpr size_t OFF_PART   = 12582912;   // 1024*32*128 = 4194304
static constexpr size_t OFF_SSP    = 16777216;   // 1024*1024  = 1048576
static constexpr size_t OFF_CAP    = 17825792;   // 1024*32
static constexpr size_t OFF_CSP    = 17858560;   // 1024*32

__device__ __forceinline__ float selu_f(float x) {
  return 1.0507009873554805f * (x > 0.f ? x : 1.6732632423543772f * expm1f(x));
}

__device__ __forceinline__ float block_sum_bcast(float v, float* sm) {
  int lane = threadIdx.x & 63, w = threadIdx.x >> 6;
#pragma unroll
  for (int off = 32; off; off >>= 1) v += __shfl_down(v, off);
  __syncthreads();
  if (lane == 0) sm[w] = v;
  __syncthreads();
  return sm[0] + sm[1] + sm[2] + sm[3];
}

// ---- count: 128 blocks (graph x 8 partitions), private LDS hists -> global per-partition;
//      blocks 128..255: GraphNorm partials. No global atomics, no memset needed. ----
__global__ __launch_bounds__(1024) void k_count(const int* ei, const float* x,
                                                int* histin, int* histout,
                                                float* gsp, float* gsp2) { // grid 256 x 1024
  __shared__ int hin[2048], hout[2048];             // 16 KB
  __shared__ float l1[16][64], l2[16][64];          // 8 KB
  int blk = blockIdx.x;
  int tid = threadIdx.x;
  if (blk < 128) {
    int g = blk >> 3, p = blk & 7;
    int nbase = g * 2048, ebase = g * 32768 + p * 4096;
    hin[tid] = 0; hin[tid + 1024] = 0;
    hout[tid] = 0; hout[tid + 1024] = 0;
    __syncthreads();
#pragma unroll
    for (int it = 0; it < 4; it++) {
      int e = ebase + it * 1024 + tid;
      int s = ei[e], d = ei[E_ + e];
      atomicAdd(&hout[s - nbase], 1);
      atomicAdd(&hin[d - nbase], 1);
    }
    __syncthreads();
    histin[blk * 2048 + tid] = hin[tid];
    histin[blk * 2048 + tid + 1024] = hin[tid + 1024];
    histout[blk * 2048 + tid] = hout[tid];
    histout[blk * 2048 + tid + 1024] = hout[tid + 1024];
  } else {
    int gi = blk - 128;               // 0..127
    int b = gi >> 3, chunk = gi & 7;
    int c = tid & 63, r = tid >> 6;   // r: 0..15
    float s = 0.f, s2 = 0.f;
    const float* xb = x + ((size_t)b * N_ + (size_t)chunk * 256) * 64;
    for (int n = r; n < 256; n += 16) {
      float v = xb[n * 64 + c];
      s += v; s2 += v * v;
    }
    l1[r][c] = s; l2[r][c] = s2;
    __syncthreads();
    if (r == 0) {
      float t1 = 0.f, t2 = 0.f;
#pragma unroll
      for (int i = 0; i < 16; i++) { t1 += l1[i][c]; t2 += l2[i][c]; }
      gsp[gi * 64 + c] = t1;
      gsp2[gi * 64 + c] = t2;
    }
  }
}

// ---- fused (k_scan eliminated):
//      blocks 0..127: bucket for (g,p) with IN-BLOCK scan of hist -> cursors;
//        p==0 block also writes rows[]. blocks 128..2175: graphnorm normalize,
//        dinv derived inline from histin (8-value sum per node). ----
__global__ __launch_bounds__(256) void k_prepb(const float* x, const float* gsp,
                                               const float* gsp2, const float* gw,
                                               const float* gb, const float* gms,
                                               float* hsc, const int* ei,
                                               const int* histin, int* rows,
                                               int* esrc) { // grid 2176 x 256
  int tid = threadIdx.x;
  int blk = blockIdx.x;
  if (blk < 128) {
    __shared__ int tot[2048], cur[2048];   // 16 KB
    __shared__ int wsum[4];
    int g = blk >> 3, p = blk & 7;
    int nbase = g * 2048, ebase = g * 32768;
    for (int i = tid; i < 2048; i += 256) { tot[i] = 0; cur[i] = 0; }
    __syncthreads();
    for (int q = 0; q < 8; q++) {
      const int* hq = &histin[(g * 8 + q) * 2048];
      for (int i = tid; i < 2048; i += 256) {
        int v = hq[i];
        tot[i] += v;
        if (q < p) cur[i] += v;            // prefix over partitions < p
      }
    }
    __syncthreads();
    // scan 2048 totals: 8 contiguous per thread + wave shfl scan + cross-wave
    int base = tid * 8;
    int loc[8]; int run = 0;
#pragma unroll
    for (int j = 0; j < 8; j++) { loc[j] = run; run += tot[base + j]; }
    int lane = tid & 63, w = tid >> 6;
    int incl = run;
#pragma unroll
    for (int off = 1; off < 64; off <<= 1) {
      int t = __shfl_up(incl, off);
      if (lane >= off) incl += t;
    }
    if (lane == 63) wsum[w] = incl;
    __syncthreads();
    int woffv = 0;
    for (int k = 0; k < w; k++) woffv += wsum[k];
    int texcl = incl - run + woffv;        // exclusive prefix at this thread
#pragma unroll
    for (int j = 0; j < 8; j++) {
      int pre = cur[base + j];
      int rv = ebase + texcl + loc[j];
      if (p == 0) rows[nbase + base + j] = rv;
      cur[base + j] = rv + pre;
    }
    if (p == 0 && g == 15 && tid == 255) rows[NT_] = E_;
    __syncthreads();
    int ebp = ebase + p * 4096;
#pragma unroll
    for (int it = 0; it < 16; it++) {
      int e = ebp + it * 256 + tid;
      int s = ei[e], d = ei[E_ + e];
      int pos = atomicAdd(&cur[d - nbase], 1);
      esrc[pos] = s;
    }
  } else {
    __shared__ float shs[64], scs[64], sdin[16];
    int bb = blk - 128;               // 0..2047
    int bgr = bb >> 7;                // graph (128 blocks/graph, 16 nodes/block)
    int nl = (bb & 127) * 16;         // graph-local first node
    if (tid < 128) {                  // dinv for this block's 16 nodes
      int node16 = tid >> 3, q = tid & 7;
      int v = histin[(bgr * 8 + q) * 2048 + nl + node16];
      v += __shfl_down(v, 4, 8);
      v += __shfl_down(v, 2, 8);
      v += __shfl_down(v, 1, 8);
      if (q == 0) sdin[node16] = rsqrtf((float)(v + 1));
    }
    if (tid < 64) {
      float s = 0.f, s2 = 0.f;
#pragma unroll
      for (int c8 = 0; c8 < 8; c8++) {
        s  += gsp[(bgr * 8 + c8) * 64 + tid];
        s2 += gsp2[(bgr * 8 + c8) * 64 + tid];
      }
      float mean = s * (1.f / 2048.f);
      float a = gms[tid];
      float var = s2 * (1.f / 2048.f) - (2.f * a - a * a) * mean * mean;
      shs[tid] = a * mean;
      scs[tid] = gw[tid] * rsqrtf(var + 1e-5f);
    }
    __syncthreads();
    int idx = bb * 256 + tid;
    int node = idx >> 4, g4 = (idx & 15) * 4;
    float di = sdin[tid >> 4];
    float4 xv = *(const float4*)&x[(size_t)node * 64 + g4];
    float4 bbv = *(const float4*)&gb[g4];
    float4 o;
    o.x = ((xv.x - shs[g4])     * scs[g4]     + bbv.x) * di;
    o.y = ((xv.y - shs[g4 + 1]) * scs[g4 + 1] + bbv.y) * di;
    o.z = ((xv.z - shs[g4 + 2]) * scs[g4 + 2] + bbv.z) * di;
    o.w = ((xv.w - shs[g4 + 3]) * scs[g4 + 3] + bbv.w) * di;
    *(float4*)&hsc[(size_t)node * 64 + g4] = o;
  }
}

// ---- Round-21: 32-node tiles, grid 1024 (4 blocks/CU, 2x occupancy vs r20's
//      64-node/512-grid which capped at 2 blocks/CU = 18% occupancy).
//      Gather = 4 waves x 8 nodes, i<8 + unroll 1 (the EXACT proven r10 shape;
//      poison configs: 16-node tiles, 512-thr blocks -- both avoided).
//      LDS ~23 KB. GUARD: VGPR <= 96; if dur still >= 55us, occupancy wasn't
//      the lever -> revert to r8. ----
__global__ __launch_bounds__(256) void k_mm2g(const float* hsc, const int* rows,
                                              const int* esrc, const float* w1,
                                              const float* b1, const float* w2,
                                              const float* b2, const int* histout,
                                              float* outs, float* ssp,
                                              float* cap, float* csp, float* part) {
  __shared__ float xt[32 * 129];    // 16.5 KB (first 32*65 floats double as `at`)
  __shared__ float st[32 * 33];     // 4.2 KB
  __shared__ float r1[8][32], r2[8][32];
  __shared__ float cdeg[32];
  float* at = xt;
  int tid = threadIdx.x;
  int blk = blockIdx.x;             // grid 1024
  int xcd = blk & 7, slot = blk >> 3;   // slot 0..127
  int g = xcd + ((slot >> 6) << 3);     // 2 graphs/XCD (hsc slice L2-resident)
  int tile = slot & 63;                 // 64 tiles/graph
  int lt = g * 64 + tile;               // logical tile id for outputs
  int n0 = g * 2048 + tile * 32;
  int nl0 = tile * 32;
  if (tid < 32) {
    int ssum = 0;
#pragma unroll
    for (int q = 0; q < 8; q++) ssum += histout[(g * 8 + q) * 2048 + nl0 + tid];
    cdeg[tid] = (float)ssum;
  }
  // --- phase 1: CSR gather for this tile's 32 nodes (4 waves x 8 nodes) ---
  {
    int wv = tid >> 6, c = tid & 63;
#pragma unroll 1
    for (int i = 0; i < 8; i++) {
      int nn = i * 4 + wv;
      int node = n0 + nn;
      int e0 = rows[node], e1 = rows[node + 1];
      float dd = rsqrtf((float)(e1 - e0 + 1));
      float acc = hsc[(size_t)node * 64 + c];
      for (int e = e0; e < e1; e += 8) {
        int sidx[8]; float wt[8], hv[8];
#pragma unroll
        for (int j = 0; j < 8; j++) {
          int ee = e + j;
          sidx[j] = esrc[ee < e1 ? ee : e0];
          wt[j] = (ee < e1) ? 1.f : 0.f;
        }
#pragma unroll
        for (int j = 0; j < 8; j++) hv[j] = hsc[(size_t)sidx[j] * 64 + c];
#pragma unroll
        for (int j = 0; j < 8; j++) acc += wt[j] * hv[j];
      }
      at[nn * 65 + c] = dd * acc;
    }
  }
  __syncthreads();
  // --- phase 2: xd-tile = selu(at @ w1 + b1), register-staged (acc[4][4],
  //     the proven r10 register shape), into xt ---
  {
    int tx = tid & 31, ty = tid >> 5;   // ty 0..7 -> nodes ty*4..ty*4+3
    int f0 = tx * 4;
    float a1[4][4] = {};
    for (int k = 0; k < 64; k++) {
      float4 wvv = *(const float4*)&w1[k * 128 + f0];
#pragma unroll
      for (int i = 0; i < 4; i++) {
        float av = at[(ty * 4 + i) * 65 + k];
        a1[i][0] += av * wvv.x; a1[i][1] += av * wvv.y;
        a1[i][2] += av * wvv.z; a1[i][3] += av * wvv.w;
      }
    }
    float4 b1v = *(const float4*)&b1[f0];
    __syncthreads();                    // all `at` reads done before overwrite
#pragma unroll
    for (int i = 0; i < 4; i++) {
      int n = ty * 4 + i;
      xt[n * 129 + f0]     = selu_f(a1[i][0] + b1v.x);
      xt[n * 129 + f0 + 1] = selu_f(a1[i][1] + b1v.y);
      xt[n * 129 + f0 + 2] = selu_f(a1[i][2] + b1v.z);
      xt[n * 129 + f0 + 3] = selu_f(a1[i][3] + b1v.w);
    }
  }
  __syncthreads();
  // --- phase 3: s-logits = xt @ w2 + b2 (1 node per thread-row) ---
  {
    int ty = tid >> 3;                  // 0..31 -> node
    int k0 = (tid & 7) * 4;
    float a0 = 0, a1v = 0, a2 = 0, a3 = 0;
    for (int j = 0; j < 128; j++) {
      float4 wv = *(const float4*)&w2[j * 32 + k0];
      float x0 = xt[ty * 129 + j];
      a0 += x0 * wv.x; a1v += x0 * wv.y; a2 += x0 * wv.z; a3 += x0 * wv.w;
    }
    float4 bv2 = *(const float4*)&b2[k0];
    st[ty * 33 + k0]     = a0 + bv2.x;
    st[ty * 33 + k0 + 1] = a1v + bv2.y;
    st[ty * 33 + k0 + 2] = a2 + bv2.z;
    st[ty * 33 + k0 + 3] = a3 + bv2.w;
  }
  __syncthreads();
  {
    // softmax: 8 lanes per row, 4 k's per lane, shfl_xor width-8 reductions
    int n = tid >> 3, q = (tid & 7) * 4;
    float m = -3.4e38f;
#pragma unroll
    for (int j = 0; j < 4; j++) m = fmaxf(m, st[n * 33 + q + j]);
#pragma unroll
    for (int off = 1; off < 8; off <<= 1) m = fmaxf(m, __shfl_xor(m, off, 8));
    float ev[4]; float ssum = 0.f;
#pragma unroll
    for (int j = 0; j < 4; j++) { ev[j] = expf(st[n * 33 + q + j] - m); ssum += ev[j]; }
#pragma unroll
    for (int off = 1; off < 8; off <<= 1) ssum += __shfl_xor(ssum, off, 8);
    float inv = 1.f / ssum;
#pragma unroll
    for (int j = 0; j < 4; j++) st[n * 33 + q + j] = ev[j] * inv;
  }
  __syncthreads();
  {
    int n = tid >> 3, q = (tid & 7) * 4;
    float* op = &outs[(size_t)(n0 + n) * 32 + q];
    op[0] = st[n * 33 + q];
    op[1] = st[n * 33 + q + 1];
    op[2] = st[n * 33 + q + 2];
    op[3] = st[n * 33 + q + 3];
  }
  {
    int k = tid >> 3, l0 = (tid & 7) * 4;
    float a0 = 0, a1 = 0, a2 = 0, a3 = 0;
    for (int n = 0; n < 32; n++) {
      float sk = st[n * 33 + k];
      a0 += sk * st[n * 33 + l0];     a1 += sk * st[n * 33 + l0 + 1];
      a2 += sk * st[n * 33 + l0 + 2]; a3 += sk * st[n * 33 + l0 + 3];
    }
    float4 o = {a0, a1, a2, a3};
    *(float4*)&ssp[(size_t)lt * 1024 + k * 32 + l0] = o;
  }
  {
    int k2 = tid & 31, r = tid >> 5;   // r 0..7, 4 nodes each
    float aca = 0.f, acs = 0.f;
#pragma unroll
    for (int i = 0; i < 4; i++) {
      int n = i * 8 + r;
      float dg = cdeg[n];
      float v = st[n * 33 + k2];
      acs += v; aca += v * dg;
    }
    r1[r][k2] = aca; r2[r][k2] = acs;
    __syncthreads();
    if (r == 0) {
      float sa = 0.f, sc = 0.f;
#pragma unroll
      for (int i = 0; i < 8; i++) { sa += r1[i][k2]; sc += r2[i][k2]; }
      cap[lt * 32 + k2] = sa;
      csp[lt * 32 + k2] = sc;
    }
  }
  {
    int tx = tid & 31, ty2 = tid >> 5;
    int f0 = tx * 4, kk0 = ty2 * 4;
    float acc[4][4] = {};
    for (int n = 0; n < 32; n++) {
      float s0 = st[n * 33 + kk0], s1 = st[n * 33 + kk0 + 1];
      float s2 = st[n * 33 + kk0 + 2], s3 = st[n * 33 + kk0 + 3];
      float4 xv = {xt[n * 129 + f0], xt[n * 129 + f0 + 1], xt[n * 129 + f0 + 2], xt[n * 129 + f0 + 3]};
      acc[0][0] += s0 * xv.x; acc[0][1] += s0 * xv.y; acc[0][2] += s0 * xv.z; acc[0][3] += s0 * xv.w;
      acc[1][0] += s1 * xv.x; acc[1][1] += s1 * xv.y; acc[1][2] += s1 * xv.z; acc[1][3] += s1 * xv.w;
      acc[2][0] += s2 * xv.x; acc[2][1] += s2 * xv.y; acc[2][2] += s2 * xv.z; acc[2][3] += s2 * xv.w;
      acc[3][0] += s3 * xv.x; acc[3][1] += s3 * xv.y; acc[3][2] += s3 * xv.z; acc[3][3] += s3 * xv.w;
    }
#pragma unroll
    for (int i = 0; i < 4; i++) {
      float4 o = {acc[i][0], acc[i][1], acc[i][2], acc[i][3]};
      *(float4*)&part[(size_t)(lt * 32 + kk0 + i) * 128 + f0] = o;
    }
  }
}

// ---- spec partials + out0 log-softmax (no spin, no atomics):
//      blocks 0..1023: spec partials (XCD-swizzled) -> specp[blk];
//      blocks 1024..1279: out0 reduce+selu+log_softmax (part now 64 tiles/graph). ----
__global__ __launch_bounds__(256) void k_spec2(const int* rows, const int* esrc,
                                               const float* s, const float* part,
                                               float* specp, float* out0,
                                               float* lossp) { // grid 1280 x 256
  __shared__ float smem[8];
  int blk = blockIdx.x, tid = threadIdx.x;
  if (blk == 0 && tid == 0) lossp[0] = 0.f;
  if (blk < 1024) {
    int xcd = blk & 7, slot = blk >> 3;
    int g = xcd + ((slot >> 6) << 3);
    int grp = tid >> 5, k = tid & 31;
    int n0 = g * 2048 + (slot & 63) * 32 + grp * 4;
    float acc = 0.f;
#pragma unroll 1
    for (int i = 0; i < 4; i++) {
      int node = n0 + i;
      int e0 = rows[node], e1 = rows[node + 1];
      float sd = s[(size_t)node * 32 + k];
      float agg = 0.f;
      for (int e = e0; e < e1; e += 8) {
        int si[8]; float wt[8], sv[8];
#pragma unroll
        for (int j = 0; j < 8; j++) {
          int ee = e + j;
          si[j] = esrc[ee < e1 ? ee : e0];
          wt[j] = (ee < e1) ? 1.f : 0.f;
        }
#pragma unroll
        for (int j = 0; j < 8; j++) sv[j] = s[(size_t)si[j] * 32 + k];
#pragma unroll
        for (int j = 0; j < 8; j++) agg += wt[j] * sv[j];
      }
      acc += sd * agg;
    }
#pragma unroll
    for (int off = 16; off; off >>= 1) acc += __shfl_down(acc, off, 32);
    if (k == 0) smem[grp] = acc;
    __syncthreads();
    if (tid == 0) {
      specp[blk] = smem[0] + smem[1] + smem[2] + smem[3]
                 + smem[4] + smem[5] + smem[6] + smem[7];
    }
  } else {
    int rb = blk - 1024;
    int half = tid >> 7;            // 0/1 -> two rows per block
    int f = tid & 127;
    int row = rb * 2 + half;
    int b = row >> 5, k = row & 31;
    float v = 0.f;
#pragma unroll
    for (int c = 0; c < 64; c++) v += part[(size_t)((b * 64 + c) * 32 + k) * 128 + f];
    v = selu_f(v);
    int lane = tid & 63, w = tid >> 6;
    float m = v;
#pragma unroll
    for (int off = 32; off; off >>= 1) m = fmaxf(m, __shfl_down(m, off));
    if (lane == 0) smem[w] = m;
    __syncthreads();
    m = fmaxf(smem[half * 2], smem[half * 2 + 1]);
    float e = expf(v - m);
    float t = e;
    __syncthreads();
#pragma unroll
    for (int off = 32; off; off >>= 1) t += __shfl_down(t, off);
    if (lane == 0) smem[w] = t;
    __syncthreads();
    float tot = smem[half * 2] + smem[half * 2 + 1];
    out0[(size_t)row * 128 + f] = v - m - logf(tot);
  }
}

// ---- losses only: grid 16 x 256 (64 tiles/graph now) ----
__global__ __launch_bounds__(256) void k_fin2(const float* ssp, const float* csp,
                                              const float* cap, const float* specp,
                                              float* loss) { // grid 16 x 256
  __shared__ float sred[4];
  int b = blockIdx.x;
  int tid = threadIdx.x;
  float v0 = 0, v1 = 0, v2 = 0, v3 = 0;
  for (int c = 0; c < 64; c++) {
    float4 u = *(const float4*)&ssp[(size_t)(b * 64 + c) * 1024 + tid * 4];
    v0 += u.x; v1 += u.y; v2 += u.z; v3 += u.w;
  }
  float ssq = v0 * v0 + v1 * v1 + v2 * v2 + v3 * v3;
  ssq = block_sum_bcast(ssq, sred);
  float inv = 1.f / sqrtf(ssq);
  float dsq = 0.f;
  {
    int i0 = tid * 4;
    float vv[4] = {v0, v1, v2, v3};
#pragma unroll
    for (int jj = 0; jj < 4; jj++) {
      int i = i0 + jj;
      float d = vv[jj] * inv;
      if ((i >> 5) == (i & 31)) d -= 0.17677669529663687f;  // 1/sqrt(32)
      dsq += d * d;
    }
  }
  dsq = block_sum_bcast(dsq, sred);
  float csq = 0.f, casq = 0.f;
  if (tid < 32) {
    float c1 = 0.f, c2 = 0.f;
    for (int c = 0; c < 64; c++) {
      c1 += csp[(size_t)(b * 64 + c) * 32 + tid];
      c2 += cap[(size_t)(b * 64 + c) * 32 + tid];
    }
    csq = c1 * c1; casq = c2 * c2;
  }
  csq = block_sum_bcast(csq, sred);
  casq = block_sum_bcast(casq, sred);
  // spec partials for graph b live at specp[(b&7) + 8*((b>>3)*64 + t)], t=0..63
  float spec_sum = 0.f;
  if (tid < 64) spec_sum = specp[(b & 7) + 8 * ((b >> 3) * 64 + tid)];
  spec_sum = block_sum_bcast(spec_sum, sred);
  if (tid == 0) {
    float ortho = sqrtf(dsq);
    float cl = sqrtf(csq) * (1.f / 2048.f) * 5.656854249492381f - 1.f;
    float m = 16384.f;
    float spec = -(spec_sum - casq / (2.f * m)) / (2.f * m);
    atomicAdd(loss, (spec + ortho + cl) * (1.f / 16.f));
  }
}

extern "C" void kernel_launch(void* const* d_in, const int* in_sizes, int n_in,
                              void* d_out, int out_size, void* d_ws, size_t ws_size,
                              hipStream_t stream) {
  (void)in_sizes; (void)n_in; (void)out_size; (void)ws_size;
  const float* x   = (const float*)d_in[0];
  const int*   ei  = (const int*)d_in[1];
  const float* gw  = (const float*)d_in[3];
  const float* gb  = (const float*)d_in[4];
  const float* gms = (const float*)d_in[5];
  const float* w1  = (const float*)d_in[6];
  const float* b1  = (const float*)d_in[7];
  const float* w2  = (const float*)d_in[8];
  const float* b2  = (const float*)d_in[9];
  float* out = (float*)d_out;
  float* ws  = (float*)d_ws;

  float* hsc    = ws + OFF_HSC;
  float* part   = ws + OFF_PART;
  float* gsp    = ws + OFF_GSP;
  float* gsp2   = ws + OFF_GSP2;
  float* ssp    = ws + OFF_SSP;
  float* cap    = ws + OFF_CAP;
  float* csp    = ws + OFF_CSP;
  float* specp  = ws + OFF_SWS;            // 1024 floats
  int*   histin = (int*)(ws + OFF_IHIN);
  int*   histout= (int*)(ws + OFF_IHOUT);
  int*   rows   = (int*)(ws + OFF_IROWS);
  int*   esrc   = (int*)(ws + OFF_IESRC);

  float* out0  = out;            // [B,K,HID]
  float* lossp = out + 65536;    // scalar
  float* outs  = out + 65537;    // [B,N,K]

  hipLaunchKernelGGL(k_count, dim3(256), dim3(1024), 0, stream, ei, x, histin, histout, gsp, gsp2);
  hipLaunchKernelGGL(k_prepb, dim3(2176), dim3(256), 0, stream,
                     x, gsp, gsp2, gw, gb, gms, hsc, ei, histin, rows, esrc);
  hipLaunchKernelGGL(k_mm2g, dim3(1024), dim3(256), 0, stream,
                     hsc, rows, esrc, w1, b1, w2, b2, histout,
                     outs, ssp, cap, csp, part);
  hipLaunchKernelGGL(k_spec2, dim3(1280), dim3(256), 0, stream,
                     rows, esrc, outs, part, specp, out0, lossp);
  hipLaunchKernelGGL(k_fin2, dim3(16), dim3(256), 0, stream,
                     ssp, csp, cap, specp, lossp);
}

// Round 10
// 183.471 us; speedup vs baseline: 1.0567x; 1.0567x over previous
//
#include <hip/hip_runtime.h>
#include <cmath>

static constexpr int B_  = 16;
static constexpr int N_  = 2048;
static constexpr int NT_ = 32768;
static constexpr int E_  = 524288;

// Workspace layout (float-element offsets)
static constexpr size_t OFF_HSC    = 0;          // NT_*64
static constexpr size_t OFF_SWS    = 6291456;    // specp[1024]
static constexpr size_t OFF_PART   = 7340032;    // 512*32*128
static constexpr size_t OFF_GSP    = 9437184;    // 128*64
static constexpr size_t OFF_GSP2   = 9445376;    // 128*64
static constexpr size_t OFF_SSP    = 9453568;    // 512*1024
static constexpr size_t OFF_CAP    = 9977856;    // 512*32
static constexpr size_t OFF_CSP    = 9994240;    // 512*32
// int region
static constexpr size_t OFF_IHIN   = 10043904;   // 262144 per-partition in-hists
static constexpr size_t OFF_IHOUT  = 10306048;   // 262144 per-partition out-hists
static constexpr size_t OFF_IROWS  = 10830336;   // 32772
static constexpr size_t OFF_IESRC  = 10895876;   // 524288

__device__ __forceinline__ float selu_f(float x) {
  return 1.0507009873554805f * (x > 0.f ? x : 1.6732632423543772f * expm1f(x));
}

__device__ __forceinline__ float block_sum_bcast(float v, float* sm) {
  int lane = threadIdx.x & 63, w = threadIdx.x >> 6;
#pragma unroll
  for (int off = 32; off; off >>= 1) v += __shfl_down(v, off);
  __syncthreads();
  if (lane == 0) sm[w] = v;
  __syncthreads();
  return sm[0] + sm[1] + sm[2] + sm[3];
}

// ---- count: 128 blocks (graph x 8 partitions), private LDS hists -> global per-partition;
//      blocks 128..255: GraphNorm partials. No global atomics, no memset needed. ----
__global__ __launch_bounds__(1024) void k_count(const int* ei, const float* x,
                                                int* histin, int* histout,
                                                float* gsp, float* gsp2) { // grid 256 x 1024
  __shared__ int hin[2048], hout[2048];             // 16 KB
  __shared__ float l1[16][64], l2[16][64];          // 8 KB
  int blk = blockIdx.x;
  int tid = threadIdx.x;
  if (blk < 128) {
    int g = blk >> 3, p = blk & 7;
    int nbase = g * 2048, ebase = g * 32768 + p * 4096;
    hin[tid] = 0; hin[tid + 1024] = 0;
    hout[tid] = 0; hout[tid + 1024] = 0;
    __syncthreads();
#pragma unroll
    for (int it = 0; it < 4; it++) {
      int e = ebase + it * 1024 + tid;
      int s = ei[e], d = ei[E_ + e];
      atomicAdd(&hout[s - nbase], 1);
      atomicAdd(&hin[d - nbase], 1);
    }
    __syncthreads();
    histin[blk * 2048 + tid] = hin[tid];
    histin[blk * 2048 + tid + 1024] = hin[tid + 1024];
    histout[blk * 2048 + tid] = hout[tid];
    histout[blk * 2048 + tid + 1024] = hout[tid + 1024];
  } else {
    int gi = blk - 128;               // 0..127
    int b = gi >> 3, chunk = gi & 7;
    int c = tid & 63, r = tid >> 6;   // r: 0..15
    float s = 0.f, s2 = 0.f;
    const float* xb = x + ((size_t)b * N_ + (size_t)chunk * 256) * 64;
    for (int n = r; n < 256; n += 16) {
      float v = xb[n * 64 + c];
      s += v; s2 += v * v;
    }
    l1[r][c] = s; l2[r][c] = s2;
    __syncthreads();
    if (r == 0) {
      float t1 = 0.f, t2 = 0.f;
#pragma unroll
      for (int i = 0; i < 16; i++) { t1 += l1[i][c]; t2 += l2[i][c]; }
      gsp[gi * 64 + c] = t1;
      gsp2[gi * 64 + c] = t2;
    }
  }
}

// ---- fused (k_scan eliminated):
//      blocks 0..127: bucket for (g,p) with IN-BLOCK scan of hist -> cursors;
//        p==0 block also writes rows[]. blocks 128..2175: graphnorm normalize,
//        dinv derived inline from histin (8-value sum per node). ----
__global__ __launch_bounds__(256) void k_prepb(const float* x, const float* gsp,
                                               const float* gsp2, const float* gw,
                                               const float* gb, const float* gms,
                                               float* hsc, const int* ei,
                                               const int* histin, int* rows,
                                               int* esrc) { // grid 2176 x 256
  int tid = threadIdx.x;
  int blk = blockIdx.x;
  if (blk < 128) {
    __shared__ int tot[2048], cur[2048];   // 16 KB
    __shared__ int wsum[4];
    int g = blk >> 3, p = blk & 7;
    int nbase = g * 2048, ebase = g * 32768;
    for (int i = tid; i < 2048; i += 256) { tot[i] = 0; cur[i] = 0; }
    __syncthreads();
    for (int q = 0; q < 8; q++) {
      const int* hq = &histin[(g * 8 + q) * 2048];
      for (int i = tid; i < 2048; i += 256) {
        int v = hq[i];
        tot[i] += v;
        if (q < p) cur[i] += v;            // prefix over partitions < p
      }
    }
    __syncthreads();
    // scan 2048 totals: 8 contiguous per thread + wave shfl scan + cross-wave
    int base = tid * 8;
    int loc[8]; int run = 0;
#pragma unroll
    for (int j = 0; j < 8; j++) { loc[j] = run; run += tot[base + j]; }
    int lane = tid & 63, w = tid >> 6;
    int incl = run;
#pragma unroll
    for (int off = 1; off < 64; off <<= 1) {
      int t = __shfl_up(incl, off);
      if (lane >= off) incl += t;
    }
    if (lane == 63) wsum[w] = incl;
    __syncthreads();
    int woffv = 0;
    for (int k = 0; k < w; k++) woffv += wsum[k];
    int texcl = incl - run + woffv;        // exclusive prefix at this thread
#pragma unroll
    for (int j = 0; j < 8; j++) {
      int pre = cur[base + j];
      int rv = ebase + texcl + loc[j];
      if (p == 0) rows[nbase + base + j] = rv;
      cur[base + j] = rv + pre;
    }
    if (p == 0 && g == 15 && tid == 255) rows[NT_] = E_;
    __syncthreads();
    int ebp = ebase + p * 4096;
#pragma unroll
    for (int it = 0; it < 16; it++) {
      int e = ebp + it * 256 + tid;
      int s = ei[e], d = ei[E_ + e];
      int pos = atomicAdd(&cur[d - nbase], 1);
      esrc[pos] = s;
    }
  } else {
    __shared__ float shs[64], scs[64], sdin[16];
    int bb = blk - 128;               // 0..2047
    int bgr = bb >> 7;                // graph (128 blocks/graph, 16 nodes/block)
    int nl = (bb & 127) * 16;         // graph-local first node
    if (tid < 128) {                  // dinv for this block's 16 nodes
      int node16 = tid >> 3, q = tid & 7;
      int v = histin[(bgr * 8 + q) * 2048 + nl + node16];
      v += __shfl_down(v, 4, 8);
      v += __shfl_down(v, 2, 8);
      v += __shfl_down(v, 1, 8);
      if (q == 0) sdin[node16] = rsqrtf((float)(v + 1));
    }
    if (tid < 64) {
      float s = 0.f, s2 = 0.f;
#pragma unroll
      for (int c8 = 0; c8 < 8; c8++) {
        s  += gsp[(bgr * 8 + c8) * 64 + tid];
        s2 += gsp2[(bgr * 8 + c8) * 64 + tid];
      }
      float mean = s * (1.f / 2048.f);
      float a = gms[tid];
      float var = s2 * (1.f / 2048.f) - (2.f * a - a * a) * mean * mean;
      shs[tid] = a * mean;
      scs[tid] = gw[tid] * rsqrtf(var + 1e-5f);
    }
    __syncthreads();
    int idx = bb * 256 + tid;
    int node = idx >> 4, g4 = (idx & 15) * 4;
    float di = sdin[tid >> 4];
    float4 xv = *(const float4*)&x[(size_t)node * 64 + g4];
    float4 bbv = *(const float4*)&gb[g4];
    float4 o;
    o.x = ((xv.x - shs[g4])     * scs[g4]     + bbv.x) * di;
    o.y = ((xv.y - shs[g4 + 1]) * scs[g4 + 1] + bbv.y) * di;
    o.z = ((xv.z - shs[g4 + 2]) * scs[g4 + 2] + bbv.z) * di;
    o.w = ((xv.w - shs[g4 + 3]) * scs[g4 + 3] + bbv.w) * di;
    *(float4*)&hsc[(size_t)node * 64 + g4] = o;
  }
}

// ---- Round-22: r8 mega-fusion + LDS float4 vectorization.
//      Strides re-padded for 16B alignment: xt 129->132, at 65->68, st 33->36
//      (all stride%4==0 for b128; stride%32==4 for bank stagger).
//      Phase 2/3/part/softmax read LDS via ds_read_b128 (was scalar b32 --
//      "Common mistake #2 of CDNA": ~4x fewer LDS-issue slots).
//      Tile/grid/gather shape byte-identical to r8 (the only proven-safe point:
//      16-node tiles & 512-thr blocks are VGPR poison, r11/12/16/18).
//      GUARD: VGPR <= 96; if total >= 184, issue-count theory wrong -> revert r5.
__global__ __launch_bounds__(256) void k_mm2g(const float* hsc, const int* rows,
                                              const int* esrc, const float* w1,
                                              const float* b1, const float* w2,
                                              const float* b2, const int* histout,
                                              float* outs, float* ssp,
                                              float* cap, float* csp, float* part) {
  __shared__ float xt[64 * 132];    // 33.8 KB (first 64*68 floats double as `at`)
  __shared__ float st[64 * 36];     // 9.2 KB
  __shared__ float r1[8][32], r2[8][32];
  __shared__ float cdeg[64];
  float* at = xt;
  int tid = threadIdx.x;
  int blk = blockIdx.x;             // grid 512
  int xcd = blk & 7, slot = blk >> 3;   // slot 0..63
  int g = xcd + ((slot >> 5) << 3);     // 2 graphs/XCD (hsc slice L2-resident)
  int tile = slot & 31;                 // 32 tiles/graph
  int lt = g * 32 + tile;               // logical tile id for outputs
  int n0 = g * 2048 + tile * 64;
  int nl0 = tile * 64;
  if (tid < 64) {
    int ssum = 0;
#pragma unroll
    for (int q = 0; q < 8; q++) ssum += histout[(g * 8 + q) * 2048 + nl0 + tid];
    cdeg[tid] = (float)ssum;
  }
  // --- phase 1: CSR gather for this tile's 64 nodes (4 waves x 16 nodes) ---
  {
    int wv = tid >> 6, c = tid & 63;
#pragma unroll 1
    for (int i = 0; i < 16; i++) {
      int nn = i * 4 + wv;
      int node = n0 + nn;
      int e0 = rows[node], e1 = rows[node + 1];
      float dd = rsqrtf((float)(e1 - e0 + 1));
      float acc = hsc[(size_t)node * 64 + c];
      for (int e = e0; e < e1; e += 8) {
        int sidx[8]; float wt[8], hv[8];
#pragma unroll
        for (int j = 0; j < 8; j++) {
          int ee = e + j;
          sidx[j] = esrc[ee < e1 ? ee : e0];
          wt[j] = (ee < e1) ? 1.f : 0.f;
        }
#pragma unroll
        for (int j = 0; j < 8; j++) hv[j] = hsc[(size_t)sidx[j] * 64 + c];
#pragma unroll
        for (int j = 0; j < 8; j++) acc += wt[j] * hv[j];
      }
      at[nn * 68 + c] = dd * acc;
    }
  }
  __syncthreads();
  // --- phase 2: xd-tile = selu(at @ w1 + b1), k blocked by 4, b128 LDS reads ---
  {
    int tx = tid & 31, ty = tid >> 5;   // ty 0..7 -> nodes ty*8..ty*8+7
    int f0 = tx * 4;
    float a1[8][4] = {};
    for (int k4 = 0; k4 < 64; k4 += 4) {
      float4 w0 = *(const float4*)&w1[(k4 + 0) * 128 + f0];
      float4 wv1 = *(const float4*)&w1[(k4 + 1) * 128 + f0];
      float4 wv2 = *(const float4*)&w1[(k4 + 2) * 128 + f0];
      float4 wv3 = *(const float4*)&w1[(k4 + 3) * 128 + f0];
#pragma unroll
      for (int i = 0; i < 8; i++) {
        float4 av = *(const float4*)&at[(ty * 8 + i) * 68 + k4];
        a1[i][0] += av.x * w0.x + av.y * wv1.x + av.z * wv2.x + av.w * wv3.x;
        a1[i][1] += av.x * w0.y + av.y * wv1.y + av.z * wv2.y + av.w * wv3.y;
        a1[i][2] += av.x * w0.z + av.y * wv1.z + av.z * wv2.z + av.w * wv3.z;
        a1[i][3] += av.x * w0.w + av.y * wv1.w + av.z * wv2.w + av.w * wv3.w;
      }
    }
    float4 b1v = *(const float4*)&b1[f0];
    __syncthreads();                    // all `at` reads done before overwrite
#pragma unroll
    for (int i = 0; i < 8; i++) {
      int n = ty * 8 + i;
      float4 o;
      o.x = selu_f(a1[i][0] + b1v.x);
      o.y = selu_f(a1[i][1] + b1v.y);
      o.z = selu_f(a1[i][2] + b1v.z);
      o.w = selu_f(a1[i][3] + b1v.w);
      *(float4*)&xt[n * 132 + f0] = o;
    }
  }
  __syncthreads();
  // --- phase 3: s-logits = xt @ w2 + b2, j blocked by 4, b128 LDS reads ---
  {
    int ty = tid >> 3;                  // 0..31 -> nodes ty*2, ty*2+1
    int k0 = (tid & 7) * 4;
    float acc2[2][4] = {};
    for (int j4 = 0; j4 < 128; j4 += 4) {
      float4 x0 = *(const float4*)&xt[(ty * 2) * 132 + j4];
      float4 x1 = *(const float4*)&xt[(ty * 2 + 1) * 132 + j4];
      float xa[4] = {x0.x, x0.y, x0.z, x0.w};
      float xb[4] = {x1.x, x1.y, x1.z, x1.w};
#pragma unroll
      for (int t = 0; t < 4; t++) {
        float4 wv = *(const float4*)&w2[(j4 + t) * 32 + k0];
        acc2[0][0] += xa[t] * wv.x; acc2[0][1] += xa[t] * wv.y;
        acc2[0][2] += xa[t] * wv.z; acc2[0][3] += xa[t] * wv.w;
        acc2[1][0] += xb[t] * wv.x; acc2[1][1] += xb[t] * wv.y;
        acc2[1][2] += xb[t] * wv.z; acc2[1][3] += xb[t] * wv.w;
      }
    }
    float4 bv2 = *(const float4*)&b2[k0];
#pragma unroll
    for (int i = 0; i < 2; i++) {
      int n = ty * 2 + i;
      float4 o = {acc2[i][0] + bv2.x, acc2[i][1] + bv2.y,
                  acc2[i][2] + bv2.z, acc2[i][3] + bv2.w};
      *(float4*)&st[n * 36 + k0] = o;
    }
  }
  __syncthreads();
  {
    // softmax: 4 lanes per row, 8 k's per lane (2x float4), width-4 shfl_xor
    int n = tid >> 2, q = (tid & 3) * 8;
    float4 v0 = *(const float4*)&st[n * 36 + q];
    float4 v1 = *(const float4*)&st[n * 36 + q + 4];
    float m = fmaxf(fmaxf(fmaxf(v0.x, v0.y), fmaxf(v0.z, v0.w)),
                    fmaxf(fmaxf(v1.x, v1.y), fmaxf(v1.z, v1.w)));
#pragma unroll
    for (int off = 1; off < 4; off <<= 1) m = fmaxf(m, __shfl_xor(m, off, 4));
    v0.x = expf(v0.x - m); v0.y = expf(v0.y - m);
    v0.z = expf(v0.z - m); v0.w = expf(v0.w - m);
    v1.x = expf(v1.x - m); v1.y = expf(v1.y - m);
    v1.z = expf(v1.z - m); v1.w = expf(v1.w - m);
    float ssum = v0.x + v0.y + v0.z + v0.w + v1.x + v1.y + v1.z + v1.w;
#pragma unroll
    for (int off = 1; off < 4; off <<= 1) ssum += __shfl_xor(ssum, off, 4);
    float inv = 1.f / ssum;
    v0.x *= inv; v0.y *= inv; v0.z *= inv; v0.w *= inv;
    v1.x *= inv; v1.y *= inv; v1.z *= inv; v1.w *= inv;
    *(float4*)&st[n * 36 + q] = v0;
    *(float4*)&st[n * 36 + q + 4] = v1;
  }
  __syncthreads();
  for (int i = tid; i < 512; i += 256) {
    int n = i >> 3, q = (i & 7) * 4;
    float4 o = *(const float4*)&st[n * 36 + q];
    float* op = &outs[(size_t)(n0 + n) * 32 + q];   // outs base not 16B-aligned
    op[0] = o.x; op[1] = o.y; op[2] = o.z; op[3] = o.w;
  }
  {
    int k = tid >> 3, l0 = (tid & 7) * 4;
    float a0 = 0, a1 = 0, a2 = 0, a3 = 0;
    for (int n = 0; n < 64; n++) {
      float sk = st[n * 36 + k];
      float4 sl = *(const float4*)&st[n * 36 + l0];
      a0 += sk * sl.x; a1 += sk * sl.y; a2 += sk * sl.z; a3 += sk * sl.w;
    }
    float4 o = {a0, a1, a2, a3};
    *(float4*)&ssp[(size_t)lt * 1024 + k * 32 + l0] = o;
  }
  {
    int k2 = tid & 31, r = tid >> 5;
    float aca = 0.f, acs = 0.f;
    for (int i = 0; i < 8; i++) {
      int n = i * 8 + r;
      float dg = cdeg[n];
      float v = st[n * 36 + k2];
      acs += v; aca += v * dg;
    }
    r1[r][k2] = aca; r2[r][k2] = acs;
    __syncthreads();
    if (r == 0) {
      float sa = 0.f, sc = 0.f;
#pragma unroll
      for (int i = 0; i < 8; i++) { sa += r1[i][k2]; sc += r2[i][k2]; }
      cap[lt * 32 + k2] = sa;
      csp[lt * 32 + k2] = sc;
    }
  }
  {
    int tx = tid & 31, ty2 = tid >> 5;
    int f0 = tx * 4, kk0 = ty2 * 4;
    float acc[4][4] = {};
    for (int n = 0; n < 64; n++) {
      float4 sv = *(const float4*)&st[n * 36 + kk0];
      float4 xv = *(const float4*)&xt[n * 132 + f0];
      acc[0][0] += sv.x * xv.x; acc[0][1] += sv.x * xv.y; acc[0][2] += sv.x * xv.z; acc[0][3] += sv.x * xv.w;
      acc[1][0] += sv.y * xv.x; acc[1][1] += sv.y * xv.y; acc[1][2] += sv.y * xv.z; acc[1][3] += sv.y * xv.w;
      acc[2][0] += sv.z * xv.x; acc[2][1] += sv.z * xv.y; acc[2][2] += sv.z * xv.z; acc[2][3] += sv.z * xv.w;
      acc[3][0] += sv.w * xv.x; acc[3][1] += sv.w * xv.y; acc[3][2] += sv.w * xv.z; acc[3][3] += sv.w * xv.w;
    }
#pragma unroll
    for (int i = 0; i < 4; i++) {
      float4 o = {acc[i][0], acc[i][1], acc[i][2], acc[i][3]};
      *(float4*)&part[(size_t)(lt * 32 + kk0 + i) * 128 + f0] = o;
    }
  }
}

// ---- spec partials + out0 log-softmax (no spin, no atomics):
//      blocks 0..1023: spec partials (XCD-swizzled) -> specp[blk];
//      blocks 1024..1279: out0 reduce+selu+log_softmax (independent of spec). ----
__global__ __launch_bounds__(256) void k_spec2(const int* rows, const int* esrc,
                                               const float* s, const float* part,
                                               float* specp, float* out0,
                                               float* lossp) { // grid 1280 x 256
  __shared__ float smem[8];
  int blk = blockIdx.x, tid = threadIdx.x;
  if (blk == 0 && tid == 0) lossp[0] = 0.f;
  if (blk < 1024) {
    int xcd = blk & 7, slot = blk >> 3;
    int g = xcd + ((slot >> 6) << 3);
    int grp = tid >> 5, k = tid & 31;
    int n0 = g * 2048 + (slot & 63) * 32 + grp * 4;
    float acc = 0.f;
#pragma unroll 1
    for (int i = 0; i < 4; i++) {
      int node = n0 + i;
      int e0 = rows[node], e1 = rows[node + 1];
      float sd = s[(size_t)node * 32 + k];
      float agg = 0.f;
      for (int e = e0; e < e1; e += 8) {
        int si[8]; float wt[8], sv[8];
#pragma unroll
        for (int j = 0; j < 8; j++) {
          int ee = e + j;
          si[j] = esrc[ee < e1 ? ee : e0];
          wt[j] = (ee < e1) ? 1.f : 0.f;
        }
#pragma unroll
        for (int j = 0; j < 8; j++) sv[j] = s[(size_t)si[j] * 32 + k];
#pragma unroll
        for (int j = 0; j < 8; j++) agg += wt[j] * sv[j];
      }
      acc += sd * agg;
    }
#pragma unroll
    for (int off = 16; off; off >>= 1) acc += __shfl_down(acc, off, 32);
    if (k == 0) smem[grp] = acc;
    __syncthreads();
    if (tid == 0) {
      specp[blk] = smem[0] + smem[1] + smem[2] + smem[3]
                 + smem[4] + smem[5] + smem[6] + smem[7];
    }
  } else {
    int rb = blk - 1024;
    int half = tid >> 7;            // 0/1 -> two rows per block
    int f = tid & 127;
    int row = rb * 2 + half;
    int b = row >> 5, k = row & 31;
    float v = 0.f;
#pragma unroll
    for (int c = 0; c < 32; c++) v += part[(size_t)((b * 32 + c) * 32 + k) * 128 + f];
    v = selu_f(v);
    int lane = tid & 63, w = tid >> 6;
    float m = v;
#pragma unroll
    for (int off = 32; off; off >>= 1) m = fmaxf(m, __shfl_down(m, off));
    if (lane == 0) smem[w] = m;
    __syncthreads();
    m = fmaxf(smem[half * 2], smem[half * 2 + 1]);
    float e = expf(v - m);
    float t = e;
    __syncthreads();
#pragma unroll
    for (int off = 32; off; off >>= 1) t += __shfl_down(t, off);
    if (lane == 0) smem[w] = t;
    __syncthreads();
    float tot = smem[half * 2] + smem[half * 2 + 1];
    out0[(size_t)row * 128 + f] = v - m - logf(tot);
  }
}

// ---- losses only: grid 16 x 256 ----
__global__ __launch_bounds__(256) void k_fin2(const float* ssp, const float* csp,
                                              const float* cap, const float* specp,
                                              float* loss) { // grid 16 x 256
  __shared__ float sred[4];
  int b = blockIdx.x;
  int tid = threadIdx.x;
  float v0 = 0, v1 = 0, v2 = 0, v3 = 0;
  for (int c = 0; c < 32; c++) {
    float4 u = *(const float4*)&ssp[(size_t)(b * 32 + c) * 1024 + tid * 4];
    v0 += u.x; v1 += u.y; v2 += u.z; v3 += u.w;
  }
  float ssq = v0 * v0 + v1 * v1 + v2 * v2 + v3 * v3;
  ssq = block_sum_bcast(ssq, sred);
  float inv = 1.f / sqrtf(ssq);
  float dsq = 0.f;
  {
    int i0 = tid * 4;
    float vv[4] = {v0, v1, v2, v3};
#pragma unroll
    for (int jj = 0; jj < 4; jj++) {
      int i = i0 + jj;
      float d = vv[jj] * inv;
      if ((i >> 5) == (i & 31)) d -= 0.17677669529663687f;  // 1/sqrt(32)
      dsq += d * d;
    }
  }
  dsq = block_sum_bcast(dsq, sred);
  float csq = 0.f, casq = 0.f;
  if (tid < 32) {
    float c1 = 0.f, c2 = 0.f;
    for (int c = 0; c < 32; c++) {
      c1 += csp[(size_t)(b * 32 + c) * 32 + tid];
      c2 += cap[(size_t)(b * 32 + c) * 32 + tid];
    }
    csq = c1 * c1; casq = c2 * c2;
  }
  csq = block_sum_bcast(csq, sred);
  casq = block_sum_bcast(casq, sred);
  // spec partials for graph b live at specp[(b&7) + 8*((b>>3)*64 + t)], t=0..63
  float spec_sum = 0.f;
  if (tid < 64) spec_sum = specp[(b & 7) + 8 * ((b >> 3) * 64 + tid)];
  spec_sum = block_sum_bcast(spec_sum, sred);
  if (tid == 0) {
    float ortho = sqrtf(dsq);
    float cl = sqrtf(csq) * (1.f / 2048.f) * 5.656854249492381f - 1.f;
    float m = 16384.f;
    float spec = -(spec_sum - casq / (2.f * m)) / (2.f * m);
    atomicAdd(loss, (spec + ortho + cl) * (1.f / 16.f));
  }
}

extern "C" void kernel_launch(void* const* d_in, const int* in_sizes, int n_in,
                              void* d_out, int out_size, void* d_ws, size_t ws_size,
                              hipStream_t stream) {
  (void)in_sizes; (void)n_in; (void)out_size; (void)ws_size;
  const float* x   = (const float*)d_in[0];
  const int*   ei  = (const int*)d_in[1];
  const float* gw  = (const float*)d_in[3];
  const float* gb  = (const float*)d_in[4];
  const float* gms = (const float*)d_in[5];
  const float* w1  = (const float*)d_in[6];
  const float* b1  = (const float*)d_in[7];
  const float* w2  = (const float*)d_in[8];
  const float* b2  = (const float*)d_in[9];
  float* out = (float*)d_out;
  float* ws  = (float*)d_ws;

  float* hsc    = ws + OFF_HSC;
  float* part   = ws + OFF_PART;
  float* gsp    = ws + OFF_GSP;
  float* gsp2   = ws + OFF_GSP2;
  float* ssp    = ws + OFF_SSP;
  float* cap    = ws + OFF_CAP;
  float* csp    = ws + OFF_CSP;
  float* specp  = ws + OFF_SWS;            // 1024 floats
  int*   histin = (int*)(ws + OFF_IHIN);
  int*   histout= (int*)(ws + OFF_IHOUT);
  int*   rows   = (int*)(ws + OFF_IROWS);
  int*   esrc   = (int*)(ws + OFF_IESRC);

  float* out0  = out;            // [B,K,HID]
  float* lossp = out + 65536;    // scalar
  float* outs  = out + 65537;    // [B,N,K]

  hipLaunchKernelGGL(k_count, dim3(256), dim3(1024), 0, stream, ei, x, histin, histout, gsp, gsp2);
  hipLaunchKernelGGL(k_prepb, dim3(2176), dim3(256), 0, stream,
                     x, gsp, gsp2, gw, gb, gms, hsc, ei, histin, rows, esrc);
  hipLaunchKernelGGL(k_mm2g, dim3(512), dim3(256), 0, stream,
                     hsc, rows, esrc, w1, b1, w2, b2, histout,
                     outs, ssp, cap, csp, part);
  hipLaunchKernelGGL(k_spec2, dim3(1280), dim3(256), 0, stream,
                     rows, esrc, outs, part, specp, out0, lossp);
  hipLaunchKernelGGL(k_fin2, dim3(16), dim3(256), 0, stream,
                     ssp, csp, cap, specp, lossp);
}

// Round 11
// 180.686 us; speedup vs baseline: 1.0730x; 1.0154x over previous
//
#include <hip/hip_runtime.h>
#include <cmath>

static constexpr int B_  = 16;
static constexpr int N_  = 2048;
static constexpr int NT_ = 32768;
static constexpr int E_  = 524288;

// Workspace layout (float-element offsets)
static constexpr size_t OFF_HSC    = 0;          // NT_*64
static constexpr size_t OFF_SWS    = 6291456;    // specp[1024]
static constexpr size_t OFF_PART   = 7340032;    // 512*32*128
static constexpr size_t OFF_GSP    = 9437184;    // 128*64
static constexpr size_t OFF_GSP2   = 9445376;    // 128*64
static constexpr size_t OFF_SSP    = 9453568;    // 512*1024
static constexpr size_t OFF_CAP    = 9977856;    // 512*32
static constexpr size_t OFF_CSP    = 9994240;    // 512*32
// int region
static constexpr size_t OFF_IHIN   = 10043904;   // 262144 per-partition in-hists
static constexpr size_t OFF_IHOUT  = 10306048;   // 262144 per-partition out-hists
static constexpr size_t OFF_IROWS  = 10830336;   // 32772
static constexpr size_t OFF_IESRC  = 10895876;   // 524288

__device__ __forceinline__ float selu_f(float x) {
  return 1.0507009873554805f * (x > 0.f ? x : 1.6732632423543772f * expm1f(x));
}

__device__ __forceinline__ float block_sum_bcast(float v, float* sm) {
  int lane = threadIdx.x & 63, w = threadIdx.x >> 6;
#pragma unroll
  for (int off = 32; off; off >>= 1) v += __shfl_down(v, off);
  __syncthreads();
  if (lane == 0) sm[w] = v;
  __syncthreads();
  return sm[0] + sm[1] + sm[2] + sm[3];
}

// ---- count: 128 blocks (graph x 8 partitions), private LDS hists -> global per-partition;
//      blocks 128..255: GraphNorm partials. No global atomics, no memset needed. ----
__global__ __launch_bounds__(1024) void k_count(const int* ei, const float* x,
                                                int* histin, int* histout,
                                                float* gsp, float* gsp2) { // grid 256 x 1024
  __shared__ int hin[2048], hout[2048];             // 16 KB
  __shared__ float l1[16][64], l2[16][64];          // 8 KB
  int blk = blockIdx.x;
  int tid = threadIdx.x;
  if (blk < 128) {
    int g = blk >> 3, p = blk & 7;
    int nbase = g * 2048, ebase = g * 32768 + p * 4096;
    hin[tid] = 0; hin[tid + 1024] = 0;
    hout[tid] = 0; hout[tid + 1024] = 0;
    __syncthreads();
#pragma unroll
    for (int it = 0; it < 4; it++) {
      int e = ebase + it * 1024 + tid;
      int s = ei[e], d = ei[E_ + e];
      atomicAdd(&hout[s - nbase], 1);
      atomicAdd(&hin[d - nbase], 1);
    }
    __syncthreads();
    histin[blk * 2048 + tid] = hin[tid];
    histin[blk * 2048 + tid + 1024] = hin[tid + 1024];
    histout[blk * 2048 + tid] = hout[tid];
    histout[blk * 2048 + tid + 1024] = hout[tid + 1024];
  } else {
    int gi = blk - 128;               // 0..127
    int b = gi >> 3, chunk = gi & 7;
    int c = tid & 63, r = tid >> 6;   // r: 0..15
    float s = 0.f, s2 = 0.f;
    const float* xb = x + ((size_t)b * N_ + (size_t)chunk * 256) * 64;
    for (int n = r; n < 256; n += 16) {
      float v = xb[n * 64 + c];
      s += v; s2 += v * v;
    }
    l1[r][c] = s; l2[r][c] = s2;
    __syncthreads();
    if (r == 0) {
      float t1 = 0.f, t2 = 0.f;
#pragma unroll
      for (int i = 0; i < 16; i++) { t1 += l1[i][c]; t2 += l2[i][c]; }
      gsp[gi * 64 + c] = t1;
      gsp2[gi * 64 + c] = t2;
    }
  }
}

// ---- fused (k_scan eliminated):
//      blocks 0..127: bucket for (g,p) with IN-BLOCK scan of hist -> cursors;
//        p==0 block also writes rows[]. blocks 128..2175: graphnorm normalize,
//        dinv derived inline from histin (8-value sum per node). ----
__global__ __launch_bounds__(256) void k_prepb(const float* x, const float* gsp,
                                               const float* gsp2, const float* gw,
                                               const float* gb, const float* gms,
                                               float* hsc, const int* ei,
                                               const int* histin, int* rows,
                                               int* esrc) { // grid 2176 x 256
  int tid = threadIdx.x;
  int blk = blockIdx.x;
  if (blk < 128) {
    __shared__ int tot[2048], cur[2048];   // 16 KB
    __shared__ int wsum[4];
    int g = blk >> 3, p = blk & 7;
    int nbase = g * 2048, ebase = g * 32768;
    for (int i = tid; i < 2048; i += 256) { tot[i] = 0; cur[i] = 0; }
    __syncthreads();
    for (int q = 0; q < 8; q++) {
      const int* hq = &histin[(g * 8 + q) * 2048];
      for (int i = tid; i < 2048; i += 256) {
        int v = hq[i];
        tot[i] += v;
        if (q < p) cur[i] += v;            // prefix over partitions < p
      }
    }
    __syncthreads();
    // scan 2048 totals: 8 contiguous per thread + wave shfl scan + cross-wave
    int base = tid * 8;
    int loc[8]; int run = 0;
#pragma unroll
    for (int j = 0; j < 8; j++) { loc[j] = run; run += tot[base + j]; }
    int lane = tid & 63, w = tid >> 6;
    int incl = run;
#pragma unroll
    for (int off = 1; off < 64; off <<= 1) {
      int t = __shfl_up(incl, off);
      if (lane >= off) incl += t;
    }
    if (lane == 63) wsum[w] = incl;
    __syncthreads();
    int woffv = 0;
    for (int k = 0; k < w; k++) woffv += wsum[k];
    int texcl = incl - run + woffv;        // exclusive prefix at this thread
#pragma unroll
    for (int j = 0; j < 8; j++) {
      int pre = cur[base + j];
      int rv = ebase + texcl + loc[j];
      if (p == 0) rows[nbase + base + j] = rv;
      cur[base + j] = rv + pre;
    }
    if (p == 0 && g == 15 && tid == 255) rows[NT_] = E_;
    __syncthreads();
    int ebp = ebase + p * 4096;
#pragma unroll
    for (int it = 0; it < 16; it++) {
      int e = ebp + it * 256 + tid;
      int s = ei[e], d = ei[E_ + e];
      int pos = atomicAdd(&cur[d - nbase], 1);
      esrc[pos] = s;
    }
  } else {
    __shared__ float shs[64], scs[64], sdin[16];
    int bb = blk - 128;               // 0..2047
    int bgr = bb >> 7;                // graph (128 blocks/graph, 16 nodes/block)
    int nl = (bb & 127) * 16;         // graph-local first node
    if (tid < 128) {                  // dinv for this block's 16 nodes
      int node16 = tid >> 3, q = tid & 7;
      int v = histin[(bgr * 8 + q) * 2048 + nl + node16];
      v += __shfl_down(v, 4, 8);
      v += __shfl_down(v, 2, 8);
      v += __shfl_down(v, 1, 8);
      if (q == 0) sdin[node16] = rsqrtf((float)(v + 1));
    }
    if (tid < 64) {
      float s = 0.f, s2 = 0.f;
#pragma unroll
      for (int c8 = 0; c8 < 8; c8++) {
        s  += gsp[(bgr * 8 + c8) * 64 + tid];
        s2 += gsp2[(bgr * 8 + c8) * 64 + tid];
      }
      float mean = s * (1.f / 2048.f);
      float a = gms[tid];
      float var = s2 * (1.f / 2048.f) - (2.f * a - a * a) * mean * mean;
      shs[tid] = a * mean;
      scs[tid] = gw[tid] * rsqrtf(var + 1e-5f);
    }
    __syncthreads();
    int idx = bb * 256 + tid;
    int node = idx >> 4, g4 = (idx & 15) * 4;
    float di = sdin[tid >> 4];
    float4 xv = *(const float4*)&x[(size_t)node * 64 + g4];
    float4 bbv = *(const float4*)&gb[g4];
    float4 o;
    o.x = ((xv.x - shs[g4])     * scs[g4]     + bbv.x) * di;
    o.y = ((xv.y - shs[g4 + 1]) * scs[g4 + 1] + bbv.y) * di;
    o.z = ((xv.z - shs[g4 + 2]) * scs[g4 + 2] + bbv.z) * di;
    o.w = ((xv.w - shs[g4 + 3]) * scs[g4 + 3] + bbv.w) * di;
    *(float4*)&hsc[(size_t)node * 64 + g4] = o;
  }
}

// ---- Round-23: r10 base (mega-fusion + vectorized LDS, conflicts 2.24M->33K
//      proven FREE -- duration identical) + gather node-loop unroll 1 -> 2.
//      Rationale: r7 (TLP x8), r9 (occupancy x1.7), r10 (LDS issue /4) all
//      left k_mm2g at 58us -> the binder is the SERIAL dependent-latency chain
//      rows->esrc->hv per node, which unroll 1 forbids the compiler from
//      pipelining across nodes. unroll 2 = 2-deep software pipeline.
//      GUARD: VGPR <= ~160 (if ~256 the unroll trap fired -> revert pragmas);
//      if VGPR sane and dur unchanged -> structural floor, stop. ----
__global__ __launch_bounds__(256) void k_mm2g(const float* hsc, const int* rows,
                                              const int* esrc, const float* w1,
                                              const float* b1, const float* w2,
                                              const float* b2, const int* histout,
                                              float* outs, float* ssp,
                                              float* cap, float* csp, float* part) {
  __shared__ float xt[64 * 132];    // 33.8 KB (first 64*68 floats double as `at`)
  __shared__ float st[64 * 36];     // 9.2 KB
  __shared__ float r1[8][32], r2[8][32];
  __shared__ float cdeg[64];
  float* at = xt;
  int tid = threadIdx.x;
  int blk = blockIdx.x;             // grid 512
  int xcd = blk & 7, slot = blk >> 3;   // slot 0..63
  int g = xcd + ((slot >> 5) << 3);     // 2 graphs/XCD (hsc slice L2-resident)
  int tile = slot & 31;                 // 32 tiles/graph
  int lt = g * 32 + tile;               // logical tile id for outputs
  int n0 = g * 2048 + tile * 64;
  int nl0 = tile * 64;
  if (tid < 64) {
    int ssum = 0;
#pragma unroll
    for (int q = 0; q < 8; q++) ssum += histout[(g * 8 + q) * 2048 + nl0 + tid];
    cdeg[tid] = (float)ssum;
  }
  // --- phase 1: CSR gather for this tile's 64 nodes (4 waves x 16 nodes),
  //     2-deep pipelined across nodes (unroll 2) ---
  {
    int wv = tid >> 6, c = tid & 63;
#pragma unroll 2
    for (int i = 0; i < 16; i++) {
      int nn = i * 4 + wv;
      int node = n0 + nn;
      int e0 = rows[node], e1 = rows[node + 1];
      float dd = rsqrtf((float)(e1 - e0 + 1));
      float acc = hsc[(size_t)node * 64 + c];
      for (int e = e0; e < e1; e += 8) {
        int sidx[8]; float wt[8], hv[8];
#pragma unroll
        for (int j = 0; j < 8; j++) {
          int ee = e + j;
          sidx[j] = esrc[ee < e1 ? ee : e0];
          wt[j] = (ee < e1) ? 1.f : 0.f;
        }
#pragma unroll
        for (int j = 0; j < 8; j++) hv[j] = hsc[(size_t)sidx[j] * 64 + c];
#pragma unroll
        for (int j = 0; j < 8; j++) acc += wt[j] * hv[j];
      }
      at[nn * 68 + c] = dd * acc;
    }
  }
  __syncthreads();
  // --- phase 2: xd-tile = selu(at @ w1 + b1), k blocked by 4, b128 LDS reads ---
  {
    int tx = tid & 31, ty = tid >> 5;   // ty 0..7 -> nodes ty*8..ty*8+7
    int f0 = tx * 4;
    float a1[8][4] = {};
    for (int k4 = 0; k4 < 64; k4 += 4) {
      float4 w0 = *(const float4*)&w1[(k4 + 0) * 128 + f0];
      float4 wv1 = *(const float4*)&w1[(k4 + 1) * 128 + f0];
      float4 wv2 = *(const float4*)&w1[(k4 + 2) * 128 + f0];
      float4 wv3 = *(const float4*)&w1[(k4 + 3) * 128 + f0];
#pragma unroll
      for (int i = 0; i < 8; i++) {
        float4 av = *(const float4*)&at[(ty * 8 + i) * 68 + k4];
        a1[i][0] += av.x * w0.x + av.y * wv1.x + av.z * wv2.x + av.w * wv3.x;
        a1[i][1] += av.x * w0.y + av.y * wv1.y + av.z * wv2.y + av.w * wv3.y;
        a1[i][2] += av.x * w0.z + av.y * wv1.z + av.z * wv2.z + av.w * wv3.z;
        a1[i][3] += av.x * w0.w + av.y * wv1.w + av.z * wv2.w + av.w * wv3.w;
      }
    }
    float4 b1v = *(const float4*)&b1[f0];
    __syncthreads();                    // all `at` reads done before overwrite
#pragma unroll
    for (int i = 0; i < 8; i++) {
      int n = ty * 8 + i;
      float4 o;
      o.x = selu_f(a1[i][0] + b1v.x);
      o.y = selu_f(a1[i][1] + b1v.y);
      o.z = selu_f(a1[i][2] + b1v.z);
      o.w = selu_f(a1[i][3] + b1v.w);
      *(float4*)&xt[n * 132 + f0] = o;
    }
  }
  __syncthreads();
  // --- phase 3: s-logits = xt @ w2 + b2, j blocked by 4, b128 LDS reads ---
  {
    int ty = tid >> 3;                  // 0..31 -> nodes ty*2, ty*2+1
    int k0 = (tid & 7) * 4;
    float acc2[2][4] = {};
    for (int j4 = 0; j4 < 128; j4 += 4) {
      float4 x0 = *(const float4*)&xt[(ty * 2) * 132 + j4];
      float4 x1 = *(const float4*)&xt[(ty * 2 + 1) * 132 + j4];
      float xa[4] = {x0.x, x0.y, x0.z, x0.w};
      float xb[4] = {x1.x, x1.y, x1.z, x1.w};
#pragma unroll
      for (int t = 0; t < 4; t++) {
        float4 wv = *(const float4*)&w2[(j4 + t) * 32 + k0];
        acc2[0][0] += xa[t] * wv.x; acc2[0][1] += xa[t] * wv.y;
        acc2[0][2] += xa[t] * wv.z; acc2[0][3] += xa[t] * wv.w;
        acc2[1][0] += xb[t] * wv.x; acc2[1][1] += xb[t] * wv.y;
        acc2[1][2] += xb[t] * wv.z; acc2[1][3] += xb[t] * wv.w;
      }
    }
    float4 bv2 = *(const float4*)&b2[k0];
#pragma unroll
    for (int i = 0; i < 2; i++) {
      int n = ty * 2 + i;
      float4 o = {acc2[i][0] + bv2.x, acc2[i][1] + bv2.y,
                  acc2[i][2] + bv2.z, acc2[i][3] + bv2.w};
      *(float4*)&st[n * 36 + k0] = o;
    }
  }
  __syncthreads();
  {
    // softmax: 4 lanes per row, 8 k's per lane (2x float4), width-4 shfl_xor
    int n = tid >> 2, q = (tid & 3) * 8;
    float4 v0 = *(const float4*)&st[n * 36 + q];
    float4 v1 = *(const float4*)&st[n * 36 + q + 4];
    float m = fmaxf(fmaxf(fmaxf(v0.x, v0.y), fmaxf(v0.z, v0.w)),
                    fmaxf(fmaxf(v1.x, v1.y), fmaxf(v1.z, v1.w)));
#pragma unroll
    for (int off = 1; off < 4; off <<= 1) m = fmaxf(m, __shfl_xor(m, off, 4));
    v0.x = expf(v0.x - m); v0.y = expf(v0.y - m);
    v0.z = expf(v0.z - m); v0.w = expf(v0.w - m);
    v1.x = expf(v1.x - m); v1.y = expf(v1.y - m);
    v1.z = expf(v1.z - m); v1.w = expf(v1.w - m);
    float ssum = v0.x + v0.y + v0.z + v0.w + v1.x + v1.y + v1.z + v1.w;
#pragma unroll
    for (int off = 1; off < 4; off <<= 1) ssum += __shfl_xor(ssum, off, 4);
    float inv = 1.f / ssum;
    v0.x *= inv; v0.y *= inv; v0.z *= inv; v0.w *= inv;
    v1.x *= inv; v1.y *= inv; v1.z *= inv; v1.w *= inv;
    *(float4*)&st[n * 36 + q] = v0;
    *(float4*)&st[n * 36 + q + 4] = v1;
  }
  __syncthreads();
  for (int i = tid; i < 512; i += 256) {
    int n = i >> 3, q = (i & 7) * 4;
    float4 o = *(const float4*)&st[n * 36 + q];
    float* op = &outs[(size_t)(n0 + n) * 32 + q];   // outs base not 16B-aligned
    op[0] = o.x; op[1] = o.y; op[2] = o.z; op[3] = o.w;
  }
  {
    int k = tid >> 3, l0 = (tid & 7) * 4;
    float a0 = 0, a1 = 0, a2 = 0, a3 = 0;
    for (int n = 0; n < 64; n++) {
      float sk = st[n * 36 + k];
      float4 sl = *(const float4*)&st[n * 36 + l0];
      a0 += sk * sl.x; a1 += sk * sl.y; a2 += sk * sl.z; a3 += sk * sl.w;
    }
    float4 o = {a0, a1, a2, a3};
    *(float4*)&ssp[(size_t)lt * 1024 + k * 32 + l0] = o;
  }
  {
    int k2 = tid & 31, r = tid >> 5;
    float aca = 0.f, acs = 0.f;
    for (int i = 0; i < 8; i++) {
      int n = i * 8 + r;
      float dg = cdeg[n];
      float v = st[n * 36 + k2];
      acs += v; aca += v * dg;
    }
    r1[r][k2] = aca; r2[r][k2] = acs;
    __syncthreads();
    if (r == 0) {
      float sa = 0.f, sc = 0.f;
#pragma unroll
      for (int i = 0; i < 8; i++) { sa += r1[i][k2]; sc += r2[i][k2]; }
      cap[lt * 32 + k2] = sa;
      csp[lt * 32 + k2] = sc;
    }
  }
  {
    int tx = tid & 31, ty2 = tid >> 5;
    int f0 = tx * 4, kk0 = ty2 * 4;
    float acc[4][4] = {};
    for (int n = 0; n < 64; n++) {
      float4 sv = *(const float4*)&st[n * 36 + kk0];
      float4 xv = *(const float4*)&xt[n * 132 + f0];
      acc[0][0] += sv.x * xv.x; acc[0][1] += sv.x * xv.y; acc[0][2] += sv.x * xv.z; acc[0][3] += sv.x * xv.w;
      acc[1][0] += sv.y * xv.x; acc[1][1] += sv.y * xv.y; acc[1][2] += sv.y * xv.z; acc[1][3] += sv.y * xv.w;
      acc[2][0] += sv.z * xv.x; acc[2][1] += sv.z * xv.y; acc[2][2] += sv.z * xv.z; acc[2][3] += sv.z * xv.w;
      acc[3][0] += sv.w * xv.x; acc[3][1] += sv.w * xv.y; acc[3][2] += sv.w * xv.z; acc[3][3] += sv.w * xv.w;
    }
#pragma unroll
    for (int i = 0; i < 4; i++) {
      float4 o = {acc[i][0], acc[i][1], acc[i][2], acc[i][3]};
      *(float4*)&part[(size_t)(lt * 32 + kk0 + i) * 128 + f0] = o;
    }
  }
}

// ---- spec partials + out0 log-softmax (no spin, no atomics):
//      blocks 0..1023: spec partials (XCD-swizzled) -> specp[blk];
//      blocks 1024..1279: out0 reduce+selu+log_softmax (independent of spec).
//      Round-23: node loop unroll 1 -> 2 (same latency-pipelining rationale). ----
__global__ __launch_bounds__(256) void k_spec2(const int* rows, const int* esrc,
                                               const float* s, const float* part,
                                               float* specp, float* out0,
                                               float* lossp) { // grid 1280 x 256
  __shared__ float smem[8];
  int blk = blockIdx.x, tid = threadIdx.x;
  if (blk == 0 && tid == 0) lossp[0] = 0.f;
  if (blk < 1024) {
    int xcd = blk & 7, slot = blk >> 3;
    int g = xcd + ((slot >> 6) << 3);
    int grp = tid >> 5, k = tid & 31;
    int n0 = g * 2048 + (slot & 63) * 32 + grp * 4;
    float acc = 0.f;
#pragma unroll 2
    for (int i = 0; i < 4; i++) {
      int node = n0 + i;
      int e0 = rows[node], e1 = rows[node + 1];
      float sd = s[(size_t)node * 32 + k];
      float agg = 0.f;
      for (int e = e0; e < e1; e += 8) {
        int si[8]; float wt[8], sv[8];
#pragma unroll
        for (int j = 0; j < 8; j++) {
          int ee = e + j;
          si[j] = esrc[ee < e1 ? ee : e0];
          wt[j] = (ee < e1) ? 1.f : 0.f;
        }
#pragma unroll
        for (int j = 0; j < 8; j++) sv[j] = s[(size_t)si[j] * 32 + k];
#pragma unroll
        for (int j = 0; j < 8; j++) agg += wt[j] * sv[j];
      }
      acc += sd * agg;
    }
#pragma unroll
    for (int off = 16; off; off >>= 1) acc += __shfl_down(acc, off, 32);
    if (k == 0) smem[grp] = acc;
    __syncthreads();
    if (tid == 0) {
      specp[blk] = smem[0] + smem[1] + smem[2] + smem[3]
                 + smem[4] + smem[5] + smem[6] + smem[7];
    }
  } else {
    int rb = blk - 1024;
    int half = tid >> 7;            // 0/1 -> two rows per block
    int f = tid & 127;
    int row = rb * 2 + half;
    int b = row >> 5, k = row & 31;
    float v = 0.f;
#pragma unroll
    for (int c = 0; c < 32; c++) v += part[(size_t)((b * 32 + c) * 32 + k) * 128 + f];
    v = selu_f(v);
    int lane = tid & 63, w = tid >> 6;
    float m = v;
#pragma unroll
    for (int off = 32; off; off >>= 1) m = fmaxf(m, __shfl_down(m, off));
    if (lane == 0) smem[w] = m;
    __syncthreads();
    m = fmaxf(smem[half * 2], smem[half * 2 + 1]);
    float e = expf(v - m);
    float t = e;
    __syncthreads();
#pragma unroll
    for (int off = 32; off; off >>= 1) t += __shfl_down(t, off);
    if (lane == 0) smem[w] = t;
    __syncthreads();
    float tot = smem[half * 2] + smem[half * 2 + 1];
    out0[(size_t)row * 128 + f] = v - m - logf(tot);
  }
}

// ---- losses only: grid 16 x 256 ----
__global__ __launch_bounds__(256) void k_fin2(const float* ssp, const float* csp,
                                              const float* cap, const float* specp,
                                              float* loss) { // grid 16 x 256
  __shared__ float sred[4];
  int b = blockIdx.x;
  int tid = threadIdx.x;
  float v0 = 0, v1 = 0, v2 = 0, v3 = 0;
  for (int c = 0; c < 32; c++) {
    float4 u = *(const float4*)&ssp[(size_t)(b * 32 + c) * 1024 + tid * 4];
    v0 += u.x; v1 += u.y; v2 += u.z; v3 += u.w;
  }
  float ssq = v0 * v0 + v1 * v1 + v2 * v2 + v3 * v3;
  ssq = block_sum_bcast(ssq, sred);
  float inv = 1.f / sqrtf(ssq);
  float dsq = 0.f;
  {
    int i0 = tid * 4;
    float vv[4] = {v0, v1, v2, v3};
#pragma unroll
    for (int jj = 0; jj < 4; jj++) {
      int i = i0 + jj;
      float d = vv[jj] * inv;
      if ((i >> 5) == (i & 31)) d -= 0.17677669529663687f;  // 1/sqrt(32)
      dsq += d * d;
    }
  }
  dsq = block_sum_bcast(dsq, sred);
  float csq = 0.f, casq = 0.f;
  if (tid < 32) {
    float c1 = 0.f, c2 = 0.f;
    for (int c = 0; c < 32; c++) {
      c1 += csp[(size_t)(b * 32 + c) * 32 + tid];
      c2 += cap[(size_t)(b * 32 + c) * 32 + tid];
    }
    csq = c1 * c1; casq = c2 * c2;
  }
  csq = block_sum_bcast(csq, sred);
  casq = block_sum_bcast(casq, sred);
  // spec partials for graph b live at specp[(b&7) + 8*((b>>3)*64 + t)], t=0..63
  float spec_sum = 0.f;
  if (tid < 64) spec_sum = specp[(b & 7) + 8 * ((b >> 3) * 64 + tid)];
  spec_sum = block_sum_bcast(spec_sum, sred);
  if (tid == 0) {
    float ortho = sqrtf(dsq);
    float cl = sqrtf(csq) * (1.f / 2048.f) * 5.656854249492381f - 1.f;
    float m = 16384.f;
    float spec = -(spec_sum - casq / (2.f * m)) / (2.f * m);
    atomicAdd(loss, (spec + ortho + cl) * (1.f / 16.f));
  }
}

extern "C" void kernel_launch(void* const* d_in, const int* in_sizes, int n_in,
                              void* d_out, int out_size, void* d_ws, size_t ws_size,
                              hipStream_t stream) {
  (void)in_sizes; (void)n_in; (void)out_size; (void)ws_size;
  const float* x   = (const float*)d_in[0];
  const int*   ei  = (const int*)d_in[1];
  const float* gw  = (const float*)d_in[3];
  const float* gb  = (const float*)d_in[4];
  const float* gms = (const float*)d_in[5];
  const float* w1  = (const float*)d_in[6];
  const float* b1  = (const float*)d_in[7];
  const float* w2  = (const float*)d_in[8];
  const float* b2  = (const float*)d_in[9];
  float* out = (float*)d_out;
  float* ws  = (float*)d_ws;

  float* hsc    = ws + OFF_HSC;
  float* part   = ws + OFF_PART;
  float* gsp    = ws + OFF_GSP;
  float* gsp2   = ws + OFF_GSP2;
  float* ssp    = ws + OFF_SSP;
  float* cap    = ws + OFF_CAP;
  float* csp    = ws + OFF_CSP;
  float* specp  = ws + OFF_SWS;            // 1024 floats
  int*   histin = (int*)(ws + OFF_IHIN);
  int*   histout= (int*)(ws + OFF_IHOUT);
  int*   rows   = (int*)(ws + OFF_IROWS);
  int*   esrc   = (int*)(ws + OFF_IESRC);

  float* out0  = out;            // [B,K,HID]
  float* lossp = out + 65536;    // scalar
  float* outs  = out + 65537;    // [B,N,K]

  hipLaunchKernelGGL(k_count, dim3(256), dim3(1024), 0, stream, ei, x, histin, histout, gsp, gsp2);
  hipLaunchKernelGGL(k_prepb, dim3(2176), dim3(256), 0, stream,
                     x, gsp, gsp2, gw, gb, gms, hsc, ei, histin, rows, esrc);
  hipLaunchKernelGGL(k_mm2g, dim3(512), dim3(256), 0, stream,
                     hsc, rows, esrc, w1, b1, w2, b2, histout,
                     outs, ssp, cap, csp, part);
  hipLaunchKernelGGL(k_spec2, dim3(1280), dim3(256), 0, stream,
                     rows, esrc, outs, part, specp, out0, lossp);
  hipLaunchKernelGGL(k_fin2, dim3(16), dim3(256), 0, stream,
                     ssp, csp, cap, specp, lossp);
}

// Round 12
// 179.599 us; speedup vs baseline: 1.0795x; 1.0061x over previous
//
#include <hip/hip_runtime.h>
#include <cmath>

static constexpr int B_  = 16;
static constexpr int N_  = 2048;
static constexpr int NT_ = 32768;
static constexpr int E_  = 524288;

// Workspace layout (float-element offsets)
static constexpr size_t OFF_HSC    = 0;          // NT_*64
static constexpr size_t OFF_SWS    = 6291456;    // specp[1024]
static constexpr size_t OFF_PART   = 7340032;    // 512*32*128
static constexpr size_t OFF_GSP    = 9437184;    // 128*64
static constexpr size_t OFF_GSP2   = 9445376;    // 128*64
static constexpr size_t OFF_SSP    = 9453568;    // 512*1024
static constexpr size_t OFF_CAP    = 9977856;    // 512*32
static constexpr size_t OFF_CSP    = 9994240;    // 512*32
// int region
static constexpr size_t OFF_IHIN   = 10043904;   // 262144 per-partition in-hists
static constexpr size_t OFF_IHOUT  = 10306048;   // 262144 per-partition out-hists
static constexpr size_t OFF_IROWS  = 10830336;   // 32772
static constexpr size_t OFF_IESRC  = 10895876;   // 524288

__device__ __forceinline__ float selu_f(float x) {
  return 1.0507009873554805f * (x > 0.f ? x : 1.6732632423543772f * expm1f(x));
}

__device__ __forceinline__ float block_sum_bcast(float v, float* sm) {
  int lane = threadIdx.x & 63, w = threadIdx.x >> 6;
#pragma unroll
  for (int off = 32; off; off >>= 1) v += __shfl_down(v, off);
  __syncthreads();
  if (lane == 0) sm[w] = v;
  __syncthreads();
  return sm[0] + sm[1] + sm[2] + sm[3];
}

// ---- count: 128 blocks (graph x 8 partitions), private LDS hists -> global per-partition;
//      blocks 128..255: GraphNorm partials. No global atomics, no memset needed. ----
__global__ __launch_bounds__(1024) void k_count(const int* ei, const float* x,
                                                int* histin, int* histout,
                                                float* gsp, float* gsp2) { // grid 256 x 1024
  __shared__ int hin[2048], hout[2048];             // 16 KB
  __shared__ float l1[16][64], l2[16][64];          // 8 KB
  int blk = blockIdx.x;
  int tid = threadIdx.x;
  if (blk < 128) {
    int g = blk >> 3, p = blk & 7;
    int nbase = g * 2048, ebase = g * 32768 + p * 4096;
    hin[tid] = 0; hin[tid + 1024] = 0;
    hout[tid] = 0; hout[tid + 1024] = 0;
    __syncthreads();
#pragma unroll
    for (int it = 0; it < 4; it++) {
      int e = ebase + it * 1024 + tid;
      int s = ei[e], d = ei[E_ + e];
      atomicAdd(&hout[s - nbase], 1);
      atomicAdd(&hin[d - nbase], 1);
    }
    __syncthreads();
    histin[blk * 2048 + tid] = hin[tid];
    histin[blk * 2048 + tid + 1024] = hin[tid + 1024];
    histout[blk * 2048 + tid] = hout[tid];
    histout[blk * 2048 + tid + 1024] = hout[tid + 1024];
  } else {
    int gi = blk - 128;               // 0..127
    int b = gi >> 3, chunk = gi & 7;
    int c = tid & 63, r = tid >> 6;   // r: 0..15
    float s = 0.f, s2 = 0.f;
    const float* xb = x + ((size_t)b * N_ + (size_t)chunk * 256) * 64;
    for (int n = r; n < 256; n += 16) {
      float v = xb[n * 64 + c];
      s += v; s2 += v * v;
    }
    l1[r][c] = s; l2[r][c] = s2;
    __syncthreads();
    if (r == 0) {
      float t1 = 0.f, t2 = 0.f;
#pragma unroll
      for (int i = 0; i < 16; i++) { t1 += l1[i][c]; t2 += l2[i][c]; }
      gsp[gi * 64 + c] = t1;
      gsp2[gi * 64 + c] = t2;
    }
  }
}

// ---- fused (k_scan eliminated):
//      blocks 0..127: bucket for (g,p) with IN-BLOCK scan of hist -> cursors;
//        p==0 block also writes rows[]. blocks 128..2175: graphnorm normalize,
//        dinv derived inline from histin (8-value sum per node). ----
__global__ __launch_bounds__(256) void k_prepb(const float* x, const float* gsp,
                                               const float* gsp2, const float* gw,
                                               const float* gb, const float* gms,
                                               float* hsc, const int* ei,
                                               const int* histin, int* rows,
                                               int* esrc) { // grid 2176 x 256
  int tid = threadIdx.x;
  int blk = blockIdx.x;
  if (blk < 128) {
    __shared__ int tot[2048], cur[2048];   // 16 KB
    __shared__ int wsum[4];
    int g = blk >> 3, p = blk & 7;
    int nbase = g * 2048, ebase = g * 32768;
    for (int i = tid; i < 2048; i += 256) { tot[i] = 0; cur[i] = 0; }
    __syncthreads();
    for (int q = 0; q < 8; q++) {
      const int* hq = &histin[(g * 8 + q) * 2048];
      for (int i = tid; i < 2048; i += 256) {
        int v = hq[i];
        tot[i] += v;
        if (q < p) cur[i] += v;            // prefix over partitions < p
      }
    }
    __syncthreads();
    // scan 2048 totals: 8 contiguous per thread + wave shfl scan + cross-wave
    int base = tid * 8;
    int loc[8]; int run = 0;
#pragma unroll
    for (int j = 0; j < 8; j++) { loc[j] = run; run += tot[base + j]; }
    int lane = tid & 63, w = tid >> 6;
    int incl = run;
#pragma unroll
    for (int off = 1; off < 64; off <<= 1) {
      int t = __shfl_up(incl, off);
      if (lane >= off) incl += t;
    }
    if (lane == 63) wsum[w] = incl;
    __syncthreads();
    int woffv = 0;
    for (int k = 0; k < w; k++) woffv += wsum[k];
    int texcl = incl - run + woffv;        // exclusive prefix at this thread
#pragma unroll
    for (int j = 0; j < 8; j++) {
      int pre = cur[base + j];
      int rv = ebase + texcl + loc[j];
      if (p == 0) rows[nbase + base + j] = rv;
      cur[base + j] = rv + pre;
    }
    if (p == 0 && g == 15 && tid == 255) rows[NT_] = E_;
    __syncthreads();
    int ebp = ebase + p * 4096;
#pragma unroll
    for (int it = 0; it < 16; it++) {
      int e = ebp + it * 256 + tid;
      int s = ei[e], d = ei[E_ + e];
      int pos = atomicAdd(&cur[d - nbase], 1);
      esrc[pos] = s;
    }
  } else {
    __shared__ float shs[64], scs[64], sdin[16];
    int bb = blk - 128;               // 0..2047
    int bgr = bb >> 7;                // graph (128 blocks/graph, 16 nodes/block)
    int nl = (bb & 127) * 16;         // graph-local first node
    if (tid < 128) {                  // dinv for this block's 16 nodes
      int node16 = tid >> 3, q = tid & 7;
      int v = histin[(bgr * 8 + q) * 2048 + nl + node16];
      v += __shfl_down(v, 4, 8);
      v += __shfl_down(v, 2, 8);
      v += __shfl_down(v, 1, 8);
      if (q == 0) sdin[node16] = rsqrtf((float)(v + 1));
    }
    if (tid < 64) {
      float s = 0.f, s2 = 0.f;
#pragma unroll
      for (int c8 = 0; c8 < 8; c8++) {
        s  += gsp[(bgr * 8 + c8) * 64 + tid];
        s2 += gsp2[(bgr * 8 + c8) * 64 + tid];
      }
      float mean = s * (1.f / 2048.f);
      float a = gms[tid];
      float var = s2 * (1.f / 2048.f) - (2.f * a - a * a) * mean * mean;
      shs[tid] = a * mean;
      scs[tid] = gw[tid] * rsqrtf(var + 1e-5f);
    }
    __syncthreads();
    int idx = bb * 256 + tid;
    int node = idx >> 4, g4 = (idx & 15) * 4;
    float di = sdin[tid >> 4];
    float4 xv = *(const float4*)&x[(size_t)node * 64 + g4];
    float4 bbv = *(const float4*)&gb[g4];
    float4 o;
    o.x = ((xv.x - shs[g4])     * scs[g4]     + bbv.x) * di;
    o.y = ((xv.y - shs[g4 + 1]) * scs[g4 + 1] + bbv.y) * di;
    o.z = ((xv.z - shs[g4 + 2]) * scs[g4 + 2] + bbv.z) * di;
    o.w = ((xv.w - shs[g4 + 3]) * scs[g4 + 3] + bbv.w) * di;
    *(float4*)&hsc[(size_t)node * 64 + g4] = o;
  }
}

// ---- Round-24: SAME 64-node tile, 512 THREADS (8 waves x 8 gather-nodes).
//      Rationale: grid 512 = 2 blocks/CU; at 256 thr that's 2 waves/SIMD and
//      kernel time == one block's serial critical path (r7/r9/r10/r11 falsified
//      TLP/occupancy-via-tile/LDS-issue/unroll). 512 thr doubles waves/CU
//      (8->16) and halves per-wave work, with NO downstream changes.
//      NOT the poisons: r18's disaster was __launch_bounds__(512,8) forcing
//      VGPR=32 (spill) -- plain (512) here; r16's was 16-node tiles -- tile
//      stays 64. GUARD: VGPR < 128, hbm_bytes ~20MB (GB => scratch, revert).
__global__ __launch_bounds__(512) void k_mm2g(const float* hsc, const int* rows,
                                              const int* esrc, const float* w1,
                                              const float* b1, const float* w2,
                                              const float* b2, const int* histout,
                                              float* outs, float* ssp,
                                              float* cap, float* csp, float* part) {
  __shared__ float xt[64 * 132];    // 33.8 KB (first 64*68 floats double as `at`)
  __shared__ float st[64 * 36];     // 9.2 KB
  __shared__ float r1[16][32], r2[16][32];
  __shared__ float cdeg[64];
  float* at = xt;
  int tid = threadIdx.x;
  int blk = blockIdx.x;             // grid 512
  int xcd = blk & 7, slot = blk >> 3;   // slot 0..63
  int g = xcd + ((slot >> 5) << 3);     // 2 graphs/XCD (hsc slice L2-resident)
  int tile = slot & 31;                 // 32 tiles/graph
  int lt = g * 32 + tile;               // logical tile id for outputs
  int n0 = g * 2048 + tile * 64;
  int nl0 = tile * 64;
  if (tid < 64) {
    int ssum = 0;
#pragma unroll
    for (int q = 0; q < 8; q++) ssum += histout[(g * 8 + q) * 2048 + nl0 + tid];
    cdeg[tid] = (float)ssum;
  }
  // --- phase 1: CSR gather, 8 waves x 8 nodes (proven inner loop) ---
  {
    int wv = tid >> 6, c = tid & 63;    // wv 0..7
#pragma unroll 2
    for (int i = 0; i < 8; i++) {
      int nn = i * 8 + wv;
      int node = n0 + nn;
      int e0 = rows[node], e1 = rows[node + 1];
      float dd = rsqrtf((float)(e1 - e0 + 1));
      float acc = hsc[(size_t)node * 64 + c];
      for (int e = e0; e < e1; e += 8) {
        int sidx[8]; float wt[8], hv[8];
#pragma unroll
        for (int j = 0; j < 8; j++) {
          int ee = e + j;
          sidx[j] = esrc[ee < e1 ? ee : e0];
          wt[j] = (ee < e1) ? 1.f : 0.f;
        }
#pragma unroll
        for (int j = 0; j < 8; j++) hv[j] = hsc[(size_t)sidx[j] * 64 + c];
#pragma unroll
        for (int j = 0; j < 8; j++) acc += wt[j] * hv[j];
      }
      at[nn * 68 + c] = dd * acc;
    }
  }
  __syncthreads();
  // --- phase 2: xd-tile = selu(at @ w1 + b1); ty 0..15 -> 4 nodes each ---
  {
    int tx = tid & 31, ty = tid >> 5;   // ty 0..15
    int f0 = tx * 4;
    float a1[4][4] = {};
    for (int k4 = 0; k4 < 64; k4 += 4) {
      float4 w0 = *(const float4*)&w1[(k4 + 0) * 128 + f0];
      float4 wv1 = *(const float4*)&w1[(k4 + 1) * 128 + f0];
      float4 wv2 = *(const float4*)&w1[(k4 + 2) * 128 + f0];
      float4 wv3 = *(const float4*)&w1[(k4 + 3) * 128 + f0];
#pragma unroll
      for (int i = 0; i < 4; i++) {
        float4 av = *(const float4*)&at[(ty * 4 + i) * 68 + k4];
        a1[i][0] += av.x * w0.x + av.y * wv1.x + av.z * wv2.x + av.w * wv3.x;
        a1[i][1] += av.x * w0.y + av.y * wv1.y + av.z * wv2.y + av.w * wv3.y;
        a1[i][2] += av.x * w0.z + av.y * wv1.z + av.z * wv2.z + av.w * wv3.z;
        a1[i][3] += av.x * w0.w + av.y * wv1.w + av.z * wv2.w + av.w * wv3.w;
      }
    }
    float4 b1v = *(const float4*)&b1[f0];
    __syncthreads();                    // all `at` reads done before overwrite
#pragma unroll
    for (int i = 0; i < 4; i++) {
      int n = ty * 4 + i;
      float4 o;
      o.x = selu_f(a1[i][0] + b1v.x);
      o.y = selu_f(a1[i][1] + b1v.y);
      o.z = selu_f(a1[i][2] + b1v.z);
      o.w = selu_f(a1[i][3] + b1v.w);
      *(float4*)&xt[n * 132 + f0] = o;
    }
  }
  __syncthreads();
  // --- phase 3: s-logits = xt @ w2 + b2; one node per 8-lane group ---
  {
    int n3 = tid >> 3;                  // 0..63 -> node
    int k0 = (tid & 7) * 4;
    float a0 = 0, a1v = 0, a2 = 0, a3 = 0;
    for (int j4 = 0; j4 < 128; j4 += 4) {
      float4 x0 = *(const float4*)&xt[n3 * 132 + j4];
      float xa[4] = {x0.x, x0.y, x0.z, x0.w};
#pragma unroll
      for (int t = 0; t < 4; t++) {
        float4 wv = *(const float4*)&w2[(j4 + t) * 32 + k0];
        a0 += xa[t] * wv.x; a1v += xa[t] * wv.y;
        a2 += xa[t] * wv.z; a3 += xa[t] * wv.w;
      }
    }
    float4 bv2 = *(const float4*)&b2[k0];
    float4 o = {a0 + bv2.x, a1v + bv2.y, a2 + bv2.z, a3 + bv2.w};
    *(float4*)&st[n3 * 36 + k0] = o;
  }
  __syncthreads();
  {
    // softmax: 8 lanes per row, 4 k's per lane (1 float4), width-8 shfl_xor
    int n = tid >> 3, q = (tid & 7) * 4;
    float4 v0 = *(const float4*)&st[n * 36 + q];
    float m = fmaxf(fmaxf(v0.x, v0.y), fmaxf(v0.z, v0.w));
#pragma unroll
    for (int off = 1; off < 8; off <<= 1) m = fmaxf(m, __shfl_xor(m, off, 8));
    v0.x = expf(v0.x - m); v0.y = expf(v0.y - m);
    v0.z = expf(v0.z - m); v0.w = expf(v0.w - m);
    float ssum = v0.x + v0.y + v0.z + v0.w;
#pragma unroll
    for (int off = 1; off < 8; off <<= 1) ssum += __shfl_xor(ssum, off, 8);
    float inv = 1.f / ssum;
    v0.x *= inv; v0.y *= inv; v0.z *= inv; v0.w *= inv;
    *(float4*)&st[n * 36 + q] = v0;
  }
  __syncthreads();
  {
    // outs: 512 threads, one float4 each
    int n = tid >> 3, q = (tid & 7) * 4;
    float4 o = *(const float4*)&st[n * 36 + q];
    float* op = &outs[(size_t)(n0 + n) * 32 + q];   // outs base not 16B-aligned
    op[0] = o.x; op[1] = o.y; op[2] = o.z; op[3] = o.w;
  }
  if (tid < 256) {
    int k = tid >> 3, l0 = (tid & 7) * 4;
    float a0 = 0, a1 = 0, a2 = 0, a3 = 0;
    for (int n = 0; n < 64; n++) {
      float sk = st[n * 36 + k];
      float4 sl = *(const float4*)&st[n * 36 + l0];
      a0 += sk * sl.x; a1 += sk * sl.y; a2 += sk * sl.z; a3 += sk * sl.w;
    }
    float4 o = {a0, a1, a2, a3};
    *(float4*)&ssp[(size_t)lt * 1024 + k * 32 + l0] = o;
  }
  {
    int k2 = tid & 31, r = tid >> 5;    // r 0..15, 4 nodes each
    float aca = 0.f, acs = 0.f;
#pragma unroll
    for (int i = 0; i < 4; i++) {
      int n = i * 16 + r;
      float dg = cdeg[n];
      float v = st[n * 36 + k2];
      acs += v; aca += v * dg;
    }
    r1[r][k2] = aca; r2[r][k2] = acs;
    __syncthreads();
    if (r == 0) {
      float sa = 0.f, sc = 0.f;
#pragma unroll
      for (int i = 0; i < 16; i++) { sa += r1[i][k2]; sc += r2[i][k2]; }
      cap[lt * 32 + k2] = sa;
      csp[lt * 32 + k2] = sc;
    }
  }
  {
    // part: ty2 0..15 -> 2 k-rows each
    int tx = tid & 31, ty2 = tid >> 5;
    int f0 = tx * 4, kk0 = ty2 * 2;
    float acc[2][4] = {};
    for (int n = 0; n < 64; n++) {
      float2 sv = *(const float2*)&st[n * 36 + kk0];
      float4 xv = *(const float4*)&xt[n * 132 + f0];
      acc[0][0] += sv.x * xv.x; acc[0][1] += sv.x * xv.y; acc[0][2] += sv.x * xv.z; acc[0][3] += sv.x * xv.w;
      acc[1][0] += sv.y * xv.x; acc[1][1] += sv.y * xv.y; acc[1][2] += sv.y * xv.z; acc[1][3] += sv.y * xv.w;
    }
#pragma unroll
    for (int i = 0; i < 2; i++) {
      float4 o = {acc[i][0], acc[i][1], acc[i][2], acc[i][3]};
      *(float4*)&part[(size_t)(lt * 32 + kk0 + i) * 128 + f0] = o;
    }
  }
}

// ---- spec partials + out0 log-softmax (no spin, no atomics):
//      blocks 0..1023: spec partials (XCD-swizzled) -> specp[blk];
//      blocks 1024..1279: out0 reduce+selu+log_softmax (independent of spec).
//      node loop unroll 2 (r11: -3us). ----
__global__ __launch_bounds__(256) void k_spec2(const int* rows, const int* esrc,
                                               const float* s, const float* part,
                                               float* specp, float* out0,
                                               float* lossp) { // grid 1280 x 256
  __shared__ float smem[8];
  int blk = blockIdx.x, tid = threadIdx.x;
  if (blk == 0 && tid == 0) lossp[0] = 0.f;
  if (blk < 1024) {
    int xcd = blk & 7, slot = blk >> 3;
    int g = xcd + ((slot >> 6) << 3);
    int grp = tid >> 5, k = tid & 31;
    int n0 = g * 2048 + (slot & 63) * 32 + grp * 4;
    float acc = 0.f;
#pragma unroll 2
    for (int i = 0; i < 4; i++) {
      int node = n0 + i;
      int e0 = rows[node], e1 = rows[node + 1];
      float sd = s[(size_t)node * 32 + k];
      float agg = 0.f;
      for (int e = e0; e < e1; e += 8) {
        int si[8]; float wt[8], sv[8];
#pragma unroll
        for (int j = 0; j < 8; j++) {
          int ee = e + j;
          si[j] = esrc[ee < e1 ? ee : e0];
          wt[j] = (ee < e1) ? 1.f : 0.f;
        }
#pragma unroll
        for (int j = 0; j < 8; j++) sv[j] = s[(size_t)si[j] * 32 + k];
#pragma unroll
        for (int j = 0; j < 8; j++) agg += wt[j] * sv[j];
      }
      acc += sd * agg;
    }
#pragma unroll
    for (int off = 16; off; off >>= 1) acc += __shfl_down(acc, off, 32);
    if (k == 0) smem[grp] = acc;
    __syncthreads();
    if (tid == 0) {
      specp[blk] = smem[0] + smem[1] + smem[2] + smem[3]
                 + smem[4] + smem[5] + smem[6] + smem[7];
    }
  } else {
    int rb = blk - 1024;
    int half = tid >> 7;            // 0/1 -> two rows per block
    int f = tid & 127;
    int row = rb * 2 + half;
    int b = row >> 5, k = row & 31;
    float v = 0.f;
#pragma unroll
    for (int c = 0; c < 32; c++) v += part[(size_t)((b * 32 + c) * 32 + k) * 128 + f];
    v = selu_f(v);
    int lane = tid & 63, w = tid >> 6;
    float m = v;
#pragma unroll
    for (int off = 32; off; off >>= 1) m = fmaxf(m, __shfl_down(m, off));
    if (lane == 0) smem[w] = m;
    __syncthreads();
    m = fmaxf(smem[half * 2], smem[half * 2 + 1]);
    float e = expf(v - m);
    float t = e;
    __syncthreads();
#pragma unroll
    for (int off = 32; off; off >>= 1) t += __shfl_down(t, off);
    if (lane == 0) smem[w] = t;
    __syncthreads();
    float tot = smem[half * 2] + smem[half * 2 + 1];
    out0[(size_t)row * 128 + f] = v - m - logf(tot);
  }
}

// ---- losses only: grid 16 x 256 ----
__global__ __launch_bounds__(256) void k_fin2(const float* ssp, const float* csp,
                                              const float* cap, const float* specp,
                                              float* loss) { // grid 16 x 256
  __shared__ float sred[4];
  int b = blockIdx.x;
  int tid = threadIdx.x;
  float v0 = 0, v1 = 0, v2 = 0, v3 = 0;
  for (int c = 0; c < 32; c++) {
    float4 u = *(const float4*)&ssp[(size_t)(b * 32 + c) * 1024 + tid * 4];
    v0 += u.x; v1 += u.y; v2 += u.z; v3 += u.w;
  }
  float ssq = v0 * v0 + v1 * v1 + v2 * v2 + v3 * v3;
  ssq = block_sum_bcast(ssq, sred);
  float inv = 1.f / sqrtf(ssq);
  float dsq = 0.f;
  {
    int i0 = tid * 4;
    float vv[4] = {v0, v1, v2, v3};
#pragma unroll
    for (int jj = 0; jj < 4; jj++) {
      int i = i0 + jj;
      float d = vv[jj] * inv;
      if ((i >> 5) == (i & 31)) d -= 0.17677669529663687f;  // 1/sqrt(32)
      dsq += d * d;
    }
  }
  dsq = block_sum_bcast(dsq, sred);
  float csq = 0.f, casq = 0.f;
  if (tid < 32) {
    float c1 = 0.f, c2 = 0.f;
    for (int c = 0; c < 32; c++) {
      c1 += csp[(size_t)(b * 32 + c) * 32 + tid];
      c2 += cap[(size_t)(b * 32 + c) * 32 + tid];
    }
    csq = c1 * c1; casq = c2 * c2;
  }
  csq = block_sum_bcast(csq, sred);
  casq = block_sum_bcast(casq, sred);
  // spec partials for graph b live at specp[(b&7) + 8*((b>>3)*64 + t)], t=0..63
  float spec_sum = 0.f;
  if (tid < 64) spec_sum = specp[(b & 7) + 8 * ((b >> 3) * 64 + tid)];
  spec_sum = block_sum_bcast(spec_sum, sred);
  if (tid == 0) {
    float ortho = sqrtf(dsq);
    float cl = sqrtf(csq) * (1.f / 2048.f) * 5.656854249492381f - 1.f;
    float m = 16384.f;
    float spec = -(spec_sum - casq / (2.f * m)) / (2.f * m);
    atomicAdd(loss, (spec + ortho + cl) * (1.f / 16.f));
  }
}

extern "C" void kernel_launch(void* const* d_in, const int* in_sizes, int n_in,
                              void* d_out, int out_size, void* d_ws, size_t ws_size,
                              hipStream_t stream) {
  (void)in_sizes; (void)n_in; (void)out_size; (void)ws_size;
  const float* x   = (const float*)d_in[0];
  const int*   ei  = (const int*)d_in[1];
  const float* gw  = (const float*)d_in[3];
  const float* gb  = (const float*)d_in[4];
  const float* gms = (const float*)d_in[5];
  const float* w1  = (const float*)d_in[6];
  const float* b1  = (const float*)d_in[7];
  const float* w2  = (const float*)d_in[8];
  const float* b2  = (const float*)d_in[9];
  float* out = (float*)d_out;
  float* ws  = (float*)d_ws;

  float* hsc    = ws + OFF_HSC;
  float* part   = ws + OFF_PART;
  float* gsp    = ws + OFF_GSP;
  float* gsp2   = ws + OFF_GSP2;
  float* ssp    = ws + OFF_SSP;
  float* cap    = ws + OFF_CAP;
  float* csp    = ws + OFF_CSP;
  float* specp  = ws + OFF_SWS;            // 1024 floats
  int*   histin = (int*)(ws + OFF_IHIN);
  int*   histout= (int*)(ws + OFF_IHOUT);
  int*   rows   = (int*)(ws + OFF_IROWS);
  int*   esrc   = (int*)(ws + OFF_IESRC);

  float* out0  = out;            // [B,K,HID]
  float* lossp = out + 65536;    // scalar
  float* outs  = out + 65537;    // [B,N,K]

  hipLaunchKernelGGL(k_count, dim3(256), dim3(1024), 0, stream, ei, x, histin, histout, gsp, gsp2);
  hipLaunchKernelGGL(k_prepb, dim3(2176), dim3(256), 0, stream,
                     x, gsp, gsp2, gw, gb, gms, hsc, ei, histin, rows, esrc);
  hipLaunchKernelGGL(k_mm2g, dim3(512), dim3(512), 0, stream,
                     hsc, rows, esrc, w1, b1, w2, b2, histout,
                     outs, ssp, cap, csp, part);
  hipLaunchKernelGGL(k_spec2, dim3(1280), dim3(256), 0, stream,
                     rows, esrc, outs, part, specp, out0, lossp);
  hipLaunchKernelGGL(k_fin2, dim3(16), dim3(256), 0, stream,
                     ssp, csp, cap, specp, lossp);
}

// Round 13
// 172.866 us; speedup vs baseline: 1.1216x; 1.0389x over previous
//
#include <hip/hip_runtime.h>
#include <cmath>

static constexpr int B_  = 16;
static constexpr int N_  = 2048;
static constexpr int NT_ = 32768;
static constexpr int E_  = 524288;

// Workspace layout (float-element offsets)
static constexpr size_t OFF_HSC    = 0;          // NT_*64
static constexpr size_t OFF_SWS    = 6291456;    // specp[1024]
static constexpr size_t OFF_PART   = 7340032;    // 512*32*128
static constexpr size_t OFF_GSP    = 9437184;    // 128*64
static constexpr size_t OFF_GSP2   = 9445376;    // 128*64
static constexpr size_t OFF_SSP    = 9453568;    // 512*1024
static constexpr size_t OFF_CAP    = 9977856;    // 512*32
static constexpr size_t OFF_CSP    = 9994240;    // 512*32
// int region
static constexpr size_t OFF_IHIN   = 10043904;   // 262144 per-partition in-hists
static constexpr size_t OFF_IHOUT  = 10306048;   // 262144 per-partition out-hists
static constexpr size_t OFF_IROWS  = 10830336;   // 32772
static constexpr size_t OFF_IESRC  = 10895876;   // 524288

__device__ __forceinline__ float selu_f(float x) {
  return 1.0507009873554805f * (x > 0.f ? x : 1.6732632423543772f * expm1f(x));
}

__device__ __forceinline__ float block_sum_bcast(float v, float* sm) {
  int lane = threadIdx.x & 63, w = threadIdx.x >> 6;
#pragma unroll
  for (int off = 32; off; off >>= 1) v += __shfl_down(v, off);
  __syncthreads();
  if (lane == 0) sm[w] = v;
  __syncthreads();
  return sm[0] + sm[1] + sm[2] + sm[3];
}

// ---- count: 128 blocks (graph x 8 partitions), private LDS hists -> global per-partition;
//      blocks 128..255: GraphNorm partials. No global atomics, no memset needed. ----
__global__ __launch_bounds__(1024) void k_count(const int* ei, const float* x,
                                                int* histin, int* histout,
                                                float* gsp, float* gsp2) { // grid 256 x 1024
  __shared__ int hin[2048], hout[2048];             // 16 KB
  __shared__ float l1[16][64], l2[16][64];          // 8 KB
  int blk = blockIdx.x;
  int tid = threadIdx.x;
  if (blk < 128) {
    int g = blk >> 3, p = blk & 7;
    int nbase = g * 2048, ebase = g * 32768 + p * 4096;
    hin[tid] = 0; hin[tid + 1024] = 0;
    hout[tid] = 0; hout[tid + 1024] = 0;
    __syncthreads();
#pragma unroll
    for (int it = 0; it < 4; it++) {
      int e = ebase + it * 1024 + tid;
      int s = ei[e], d = ei[E_ + e];
      atomicAdd(&hout[s - nbase], 1);
      atomicAdd(&hin[d - nbase], 1);
    }
    __syncthreads();
    histin[blk * 2048 + tid] = hin[tid];
    histin[blk * 2048 + tid + 1024] = hin[tid + 1024];
    histout[blk * 2048 + tid] = hout[tid];
    histout[blk * 2048 + tid + 1024] = hout[tid + 1024];
  } else {
    int gi = blk - 128;               // 0..127
    int b = gi >> 3, chunk = gi & 7;
    int c = tid & 63, r = tid >> 6;   // r: 0..15
    float s = 0.f, s2 = 0.f;
    const float* xb = x + ((size_t)b * N_ + (size_t)chunk * 256) * 64;
    for (int n = r; n < 256; n += 16) {
      float v = xb[n * 64 + c];
      s += v; s2 += v * v;
    }
    l1[r][c] = s; l2[r][c] = s2;
    __syncthreads();
    if (r == 0) {
      float t1 = 0.f, t2 = 0.f;
#pragma unroll
      for (int i = 0; i < 16; i++) { t1 += l1[i][c]; t2 += l2[i][c]; }
      gsp[gi * 64 + c] = t1;
      gsp2[gi * 64 + c] = t2;
    }
  }
}

// ---- fused (k_scan eliminated):
//      blocks 0..127: bucket for (g,p) with IN-BLOCK scan of hist -> cursors;
//        p==0 block also writes rows[]. blocks 128..2175: graphnorm normalize,
//        dinv derived inline from histin (8-value sum per node). ----
__global__ __launch_bounds__(256) void k_prepb(const float* x, const float* gsp,
                                               const float* gsp2, const float* gw,
                                               const float* gb, const float* gms,
                                               float* hsc, const int* ei,
                                               const int* histin, int* rows,
                                               int* esrc) { // grid 2176 x 256
  int tid = threadIdx.x;
  int blk = blockIdx.x;
  if (blk < 128) {
    __shared__ int tot[2048], cur[2048];   // 16 KB
    __shared__ int wsum[4];
    int g = blk >> 3, p = blk & 7;
    int nbase = g * 2048, ebase = g * 32768;
    for (int i = tid; i < 2048; i += 256) { tot[i] = 0; cur[i] = 0; }
    __syncthreads();
    for (int q = 0; q < 8; q++) {
      const int* hq = &histin[(g * 8 + q) * 2048];
      for (int i = tid; i < 2048; i += 256) {
        int v = hq[i];
        tot[i] += v;
        if (q < p) cur[i] += v;            // prefix over partitions < p
      }
    }
    __syncthreads();
    // scan 2048 totals: 8 contiguous per thread + wave shfl scan + cross-wave
    int base = tid * 8;
    int loc[8]; int run = 0;
#pragma unroll
    for (int j = 0; j < 8; j++) { loc[j] = run; run += tot[base + j]; }
    int lane = tid & 63, w = tid >> 6;
    int incl = run;
#pragma unroll
    for (int off = 1; off < 64; off <<= 1) {
      int t = __shfl_up(incl, off);
      if (lane >= off) incl += t;
    }
    if (lane == 63) wsum[w] = incl;
    __syncthreads();
    int woffv = 0;
    for (int k = 0; k < w; k++) woffv += wsum[k];
    int texcl = incl - run + woffv;        // exclusive prefix at this thread
#pragma unroll
    for (int j = 0; j < 8; j++) {
      int pre = cur[base + j];
      int rv = ebase + texcl + loc[j];
      if (p == 0) rows[nbase + base + j] = rv;
      cur[base + j] = rv + pre;
    }
    if (p == 0 && g == 15 && tid == 255) rows[NT_] = E_;
    __syncthreads();
    int ebp = ebase + p * 4096;
#pragma unroll
    for (int it = 0; it < 16; it++) {
      int e = ebp + it * 256 + tid;
      int s = ei[e], d = ei[E_ + e];
      int pos = atomicAdd(&cur[d - nbase], 1);
      esrc[pos] = s;
    }
  } else {
    __shared__ float shs[64], scs[64], sdin[16];
    int bb = blk - 128;               // 0..2047
    int bgr = bb >> 7;                // graph (128 blocks/graph, 16 nodes/block)
    int nl = (bb & 127) * 16;         // graph-local first node
    if (tid < 128) {                  // dinv for this block's 16 nodes
      int node16 = tid >> 3, q = tid & 7;
      int v = histin[(bgr * 8 + q) * 2048 + nl + node16];
      v += __shfl_down(v, 4, 8);
      v += __shfl_down(v, 2, 8);
      v += __shfl_down(v, 1, 8);
      if (q == 0) sdin[node16] = rsqrtf((float)(v + 1));
    }
    if (tid < 64) {
      float s = 0.f, s2 = 0.f;
#pragma unroll
      for (int c8 = 0; c8 < 8; c8++) {
        s  += gsp[(bgr * 8 + c8) * 64 + tid];
        s2 += gsp2[(bgr * 8 + c8) * 64 + tid];
      }
      float mean = s * (1.f / 2048.f);
      float a = gms[tid];
      float var = s2 * (1.f / 2048.f) - (2.f * a - a * a) * mean * mean;
      shs[tid] = a * mean;
      scs[tid] = gw[tid] * rsqrtf(var + 1e-5f);
    }
    __syncthreads();
    int idx = bb * 256 + tid;
    int node = idx >> 4, g4 = (idx & 15) * 4;
    float di = sdin[tid >> 4];
    float4 xv = *(const float4*)&x[(size_t)node * 64 + g4];
    float4 bbv = *(const float4*)&gb[g4];
    float4 o;
    o.x = ((xv.x - shs[g4])     * scs[g4]     + bbv.x) * di;
    o.y = ((xv.y - shs[g4 + 1]) * scs[g4 + 1] + bbv.y) * di;
    o.z = ((xv.z - shs[g4 + 2]) * scs[g4 + 2] + bbv.z) * di;
    o.w = ((xv.w - shs[g4 + 3]) * scs[g4 + 3] + bbv.w) * di;
    *(float4*)&hsc[(size_t)node * 64 + g4] = o;
  }
}

// ---- Round-25: r12 base + EDGE-LIST LDS STAGING. Six falsified knobs (TLP,
//      occupancy x2, LDS-issue, bank-conflicts, unroll) say k_mm2g is bound by
//      the per-batch DEPENDENT CHAIN: esrc(L2 ~250cy) -> sidx -> hsc(L2).
//      A tile's in-edges are CONTIGUOUS in esrc (CSR by dst) -> bulk-stage them
//      into LDS once (elds aliases st, unused until phase 3; rows -> rlds[65]).
//      Per-batch chain becomes ds_read(~20cy) -> hsc load: ~halves the chain.
//      Block-uniform fallback to global path if ecnt > 2304 (statistically
//      impossible at mean 1024, but correct regardless).
//      GUARD: VGPR <= 96; if k_mm2g unchanged again -> chain theory dead,
//      ablate or declare floor next round. ----
__global__ __launch_bounds__(512) void k_mm2g(const float* hsc, const int* rows,
                                              const int* esrc, const float* w1,
                                              const float* b1, const float* w2,
                                              const float* b2, const int* histout,
                                              float* outs, float* ssp,
                                              float* cap, float* csp, float* part) {
  __shared__ float xt[64 * 132];    // 33.8 KB (first 64*68 floats double as `at`)
  __shared__ float st[64 * 36];     // 9.2 KB (doubles as elds[2304] in phase 1)
  __shared__ float r1[16][32], r2[16][32];
  __shared__ float cdeg[64];
  __shared__ int rlds[65];
  float* at = xt;
  int* elds = (int*)st;
  int tid = threadIdx.x;
  int blk = blockIdx.x;             // grid 512
  int xcd = blk & 7, slot = blk >> 3;   // slot 0..63
  int g = xcd + ((slot >> 5) << 3);     // 2 graphs/XCD (hsc slice L2-resident)
  int tile = slot & 31;                 // 32 tiles/graph
  int lt = g * 32 + tile;               // logical tile id for outputs
  int n0 = g * 2048 + tile * 64;
  int nl0 = tile * 64;
  if (tid < 64) {
    int ssum = 0;
#pragma unroll
    for (int q = 0; q < 8; q++) ssum += histout[(g * 8 + q) * 2048 + nl0 + tid];
    cdeg[tid] = (float)ssum;
  }
  if (tid < 65) rlds[tid] = rows[n0 + tid];
  __syncthreads();
  int ebase0 = rlds[0];
  int ecnt = rlds[64] - ebase0;
  if (ecnt <= 2304) {
    for (int i = tid; i < ecnt; i += 512) elds[i] = esrc[ebase0 + i];
  }
  __syncthreads();
  // --- phase 1: CSR gather, 8 waves x 8 nodes; sidx from LDS ---
  {
    int wv = tid >> 6, c = tid & 63;    // wv 0..7
    if (ecnt <= 2304) {
#pragma unroll 2
      for (int i = 0; i < 8; i++) {
        int nn = i * 8 + wv;
        int e0 = rlds[nn] - ebase0, e1 = rlds[nn + 1] - ebase0;
        float dd = rsqrtf((float)(e1 - e0 + 1));
        float acc = hsc[(size_t)(n0 + nn) * 64 + c];
        for (int e = e0; e < e1; e += 8) {
          int sidx[8]; float wt[8], hv[8];
#pragma unroll
          for (int j = 0; j < 8; j++) {
            int ee = e + j;
            sidx[j] = elds[ee < e1 ? ee : e0];
            wt[j] = (ee < e1) ? 1.f : 0.f;
          }
#pragma unroll
          for (int j = 0; j < 8; j++) hv[j] = hsc[(size_t)sidx[j] * 64 + c];
#pragma unroll
          for (int j = 0; j < 8; j++) acc += wt[j] * hv[j];
        }
        at[nn * 68 + c] = dd * acc;
      }
    } else {
#pragma unroll 2
      for (int i = 0; i < 8; i++) {
        int nn = i * 8 + wv;
        int node = n0 + nn;
        int e0 = rlds[nn], e1 = rlds[nn + 1];
        float dd = rsqrtf((float)(e1 - e0 + 1));
        float acc = hsc[(size_t)node * 64 + c];
        for (int e = e0; e < e1; e += 8) {
          int sidx[8]; float wt[8], hv[8];
#pragma unroll
          for (int j = 0; j < 8; j++) {
            int ee = e + j;
            sidx[j] = esrc[ee < e1 ? ee : e0];
            wt[j] = (ee < e1) ? 1.f : 0.f;
          }
#pragma unroll
          for (int j = 0; j < 8; j++) hv[j] = hsc[(size_t)sidx[j] * 64 + c];
#pragma unroll
          for (int j = 0; j < 8; j++) acc += wt[j] * hv[j];
        }
        at[nn * 68 + c] = dd * acc;
      }
    }
  }
  __syncthreads();
  // --- phase 2: xd-tile = selu(at @ w1 + b1); ty 0..15 -> 4 nodes each ---
  {
    int tx = tid & 31, ty = tid >> 5;   // ty 0..15
    int f0 = tx * 4;
    float a1[4][4] = {};
    for (int k4 = 0; k4 < 64; k4 += 4) {
      float4 w0 = *(const float4*)&w1[(k4 + 0) * 128 + f0];
      float4 wv1 = *(const float4*)&w1[(k4 + 1) * 128 + f0];
      float4 wv2 = *(const float4*)&w1[(k4 + 2) * 128 + f0];
      float4 wv3 = *(const float4*)&w1[(k4 + 3) * 128 + f0];
#pragma unroll
      for (int i = 0; i < 4; i++) {
        float4 av = *(const float4*)&at[(ty * 4 + i) * 68 + k4];
        a1[i][0] += av.x * w0.x + av.y * wv1.x + av.z * wv2.x + av.w * wv3.x;
        a1[i][1] += av.x * w0.y + av.y * wv1.y + av.z * wv2.y + av.w * wv3.y;
        a1[i][2] += av.x * w0.z + av.y * wv1.z + av.z * wv2.z + av.w * wv3.z;
        a1[i][3] += av.x * w0.w + av.y * wv1.w + av.z * wv2.w + av.w * wv3.w;
      }
    }
    float4 b1v = *(const float4*)&b1[f0];
    __syncthreads();                    // all `at` reads done before overwrite
#pragma unroll
    for (int i = 0; i < 4; i++) {
      int n = ty * 4 + i;
      float4 o;
      o.x = selu_f(a1[i][0] + b1v.x);
      o.y = selu_f(a1[i][1] + b1v.y);
      o.z = selu_f(a1[i][2] + b1v.z);
      o.w = selu_f(a1[i][3] + b1v.w);
      *(float4*)&xt[n * 132 + f0] = o;
    }
  }
  __syncthreads();
  // --- phase 3: s-logits = xt @ w2 + b2; one node per 8-lane group ---
  {
    int n3 = tid >> 3;                  // 0..63 -> node
    int k0 = (tid & 7) * 4;
    float a0 = 0, a1v = 0, a2 = 0, a3 = 0;
    for (int j4 = 0; j4 < 128; j4 += 4) {
      float4 x0 = *(const float4*)&xt[n3 * 132 + j4];
      float xa[4] = {x0.x, x0.y, x0.z, x0.w};
#pragma unroll
      for (int t = 0; t < 4; t++) {
        float4 wv = *(const float4*)&w2[(j4 + t) * 32 + k0];
        a0 += xa[t] * wv.x; a1v += xa[t] * wv.y;
        a2 += xa[t] * wv.z; a3 += xa[t] * wv.w;
      }
    }
    float4 bv2 = *(const float4*)&b2[k0];
    float4 o = {a0 + bv2.x, a1v + bv2.y, a2 + bv2.z, a3 + bv2.w};
    *(float4*)&st[n3 * 36 + k0] = o;
  }
  __syncthreads();
  {
    // softmax: 8 lanes per row, 4 k's per lane (1 float4), width-8 shfl_xor
    int n = tid >> 3, q = (tid & 7) * 4;
    float4 v0 = *(const float4*)&st[n * 36 + q];
    float m = fmaxf(fmaxf(v0.x, v0.y), fmaxf(v0.z, v0.w));
#pragma unroll
    for (int off = 1; off < 8; off <<= 1) m = fmaxf(m, __shfl_xor(m, off, 8));
    v0.x = expf(v0.x - m); v0.y = expf(v0.y - m);
    v0.z = expf(v0.z - m); v0.w = expf(v0.w - m);
    float ssum = v0.x + v0.y + v0.z + v0.w;
#pragma unroll
    for (int off = 1; off < 8; off <<= 1) ssum += __shfl_xor(ssum, off, 8);
    float inv = 1.f / ssum;
    v0.x *= inv; v0.y *= inv; v0.z *= inv; v0.w *= inv;
    *(float4*)&st[n * 36 + q] = v0;
  }
  __syncthreads();
  {
    // outs: 512 threads, one float4 each
    int n = tid >> 3, q = (tid & 7) * 4;
    float4 o = *(const float4*)&st[n * 36 + q];
    float* op = &outs[(size_t)(n0 + n) * 32 + q];   // outs base not 16B-aligned
    op[0] = o.x; op[1] = o.y; op[2] = o.z; op[3] = o.w;
  }
  if (tid < 256) {
    int k = tid >> 3, l0 = (tid & 7) * 4;
    float a0 = 0, a1 = 0, a2 = 0, a3 = 0;
    for (int n = 0; n < 64; n++) {
      float sk = st[n * 36 + k];
      float4 sl = *(const float4*)&st[n * 36 + l0];
      a0 += sk * sl.x; a1 += sk * sl.y; a2 += sk * sl.z; a3 += sk * sl.w;
    }
    float4 o = {a0, a1, a2, a3};
    *(float4*)&ssp[(size_t)lt * 1024 + k * 32 + l0] = o;
  }
  {
    int k2 = tid & 31, r = tid >> 5;    // r 0..15, 4 nodes each
    float aca = 0.f, acs = 0.f;
#pragma unroll
    for (int i = 0; i < 4; i++) {
      int n = i * 16 + r;
      float dg = cdeg[n];
      float v = st[n * 36 + k2];
      acs += v; aca += v * dg;
    }
    r1[r][k2] = aca; r2[r][k2] = acs;
    __syncthreads();
    if (r == 0) {
      float sa = 0.f, sc = 0.f;
#pragma unroll
      for (int i = 0; i < 16; i++) { sa += r1[i][k2]; sc += r2[i][k2]; }
      cap[lt * 32 + k2] = sa;
      csp[lt * 32 + k2] = sc;
    }
  }
  {
    // part: ty2 0..15 -> 2 k-rows each
    int tx = tid & 31, ty2 = tid >> 5;
    int f0 = tx * 4, kk0 = ty2 * 2;
    float acc[2][4] = {};
    for (int n = 0; n < 64; n++) {
      float2 sv = *(const float2*)&st[n * 36 + kk0];
      float4 xv = *(const float4*)&xt[n * 132 + f0];
      acc[0][0] += sv.x * xv.x; acc[0][1] += sv.x * xv.y; acc[0][2] += sv.x * xv.z; acc[0][3] += sv.x * xv.w;
      acc[1][0] += sv.y * xv.x; acc[1][1] += sv.y * xv.y; acc[1][2] += sv.y * xv.z; acc[1][3] += sv.y * xv.w;
    }
#pragma unroll
    for (int i = 0; i < 2; i++) {
      float4 o = {acc[i][0], acc[i][1], acc[i][2], acc[i][3]};
      *(float4*)&part[(size_t)(lt * 32 + kk0 + i) * 128 + f0] = o;
    }
  }
}

// ---- spec partials + out0 log-softmax (no spin, no atomics):
//      blocks 0..1023: spec partials (XCD-swizzled) -> specp[blk];
//      blocks 1024..1279: out0 reduce+selu+log_softmax (independent of spec).
//      Round-25: edge-list + rows LDS staging (same chain-shortening as mm2g). ----
__global__ __launch_bounds__(256) void k_spec2(const int* rows, const int* esrc,
                                               const float* s, const float* part,
                                               float* specp, float* out0,
                                               float* lossp) { // grid 1280 x 256
  __shared__ float smem[8];
  __shared__ int rl2[33];
  __shared__ int el2[1536];
  int blk = blockIdx.x, tid = threadIdx.x;
  if (blk == 0 && tid == 0) lossp[0] = 0.f;
  if (blk < 1024) {
    int xcd = blk & 7, slot = blk >> 3;
    int g = xcd + ((slot >> 6) << 3);
    int n0b = g * 2048 + (slot & 63) * 32;
    if (tid < 33) rl2[tid] = rows[n0b + tid];
    __syncthreads();
    int eb0 = rl2[0];
    int ec = rl2[32] - eb0;
    if (ec <= 1536) {
      for (int i = tid; i < ec; i += 256) el2[i] = esrc[eb0 + i];
    }
    __syncthreads();
    int grp = tid >> 5, k = tid & 31;
    int nl = grp * 4;
    float acc = 0.f;
    if (ec <= 1536) {
#pragma unroll 2
      for (int i = 0; i < 4; i++) {
        int ln = nl + i;
        int e0 = rl2[ln] - eb0, e1 = rl2[ln + 1] - eb0;
        float sd = s[(size_t)(n0b + ln) * 32 + k];
        float agg = 0.f;
        for (int e = e0; e < e1; e += 8) {
          int si[8]; float wt[8], sv[8];
#pragma unroll
          for (int j = 0; j < 8; j++) {
            int ee = e + j;
            si[j] = el2[ee < e1 ? ee : e0];
            wt[j] = (ee < e1) ? 1.f : 0.f;
          }
#pragma unroll
          for (int j = 0; j < 8; j++) sv[j] = s[(size_t)si[j] * 32 + k];
#pragma unroll
          for (int j = 0; j < 8; j++) agg += wt[j] * sv[j];
        }
        acc += sd * agg;
      }
    } else {
#pragma unroll 2
      for (int i = 0; i < 4; i++) {
        int ln = nl + i;
        int e0 = rl2[ln], e1 = rl2[ln + 1];
        float sd = s[(size_t)(n0b + ln) * 32 + k];
        float agg = 0.f;
        for (int e = e0; e < e1; e += 8) {
          int si[8]; float wt[8], sv[8];
#pragma unroll
          for (int j = 0; j < 8; j++) {
            int ee = e + j;
            si[j] = esrc[ee < e1 ? ee : e0];
            wt[j] = (ee < e1) ? 1.f : 0.f;
          }
#pragma unroll
          for (int j = 0; j < 8; j++) sv[j] = s[(size_t)si[j] * 32 + k];
#pragma unroll
          for (int j = 0; j < 8; j++) agg += wt[j] * sv[j];
        }
        acc += sd * agg;
      }
    }
#pragma unroll
    for (int off = 16; off; off >>= 1) acc += __shfl_down(acc, off, 32);
    if (k == 0) smem[grp] = acc;
    __syncthreads();
    if (tid == 0) {
      specp[blk] = smem[0] + smem[1] + smem[2] + smem[3]
                 + smem[4] + smem[5] + smem[6] + smem[7];
    }
  } else {
    int rb = blk - 1024;
    int half = tid >> 7;            // 0/1 -> two rows per block
    int f = tid & 127;
    int row = rb * 2 + half;
    int b = row >> 5, k = row & 31;
    float v = 0.f;
#pragma unroll
    for (int c = 0; c < 32; c++) v += part[(size_t)((b * 32 + c) * 32 + k) * 128 + f];
    v = selu_f(v);
    int lane = tid & 63, w = tid >> 6;
    float m = v;
#pragma unroll
    for (int off = 32; off; off >>= 1) m = fmaxf(m, __shfl_down(m, off));
    if (lane == 0) smem[w] = m;
    __syncthreads();
    m = fmaxf(smem[half * 2], smem[half * 2 + 1]);
    float e = expf(v - m);
    float t = e;
    __syncthreads();
#pragma unroll
    for (int off = 32; off; off >>= 1) t += __shfl_down(t, off);
    if (lane == 0) smem[w] = t;
    __syncthreads();
    float tot = smem[half * 2] + smem[half * 2 + 1];
    out0[(size_t)row * 128 + f] = v - m - logf(tot);
  }
}

// ---- losses only: grid 16 x 256 ----
__global__ __launch_bounds__(256) void k_fin2(const float* ssp, const float* csp,
                                              const float* cap, const float* specp,
                                              float* loss) { // grid 16 x 256
  __shared__ float sred[4];
  int b = blockIdx.x;
  int tid = threadIdx.x;
  float v0 = 0, v1 = 0, v2 = 0, v3 = 0;
  for (int c = 0; c < 32; c++) {
    float4 u = *(const float4*)&ssp[(size_t)(b * 32 + c) * 1024 + tid * 4];
    v0 += u.x; v1 += u.y; v2 += u.z; v3 += u.w;
  }
  float ssq = v0 * v0 + v1 * v1 + v2 * v2 + v3 * v3;
  ssq = block_sum_bcast(ssq, sred);
  float inv = 1.f / sqrtf(ssq);
  float dsq = 0.f;
  {
    int i0 = tid * 4;
    float vv[4] = {v0, v1, v2, v3};
#pragma unroll
    for (int jj = 0; jj < 4; jj++) {
      int i = i0 + jj;
      float d = vv[jj] * inv;
      if ((i >> 5) == (i & 31)) d -= 0.17677669529663687f;  // 1/sqrt(32)
      dsq += d * d;
    }
  }
  dsq = block_sum_bcast(dsq, sred);
  float csq = 0.f, casq = 0.f;
  if (tid < 32) {
    float c1 = 0.f, c2 = 0.f;
    for (int c = 0; c < 32; c++) {
      c1 += csp[(size_t)(b * 32 + c) * 32 + tid];
      c2 += cap[(size_t)(b * 32 + c) * 32 + tid];
    }
    csq = c1 * c1; casq = c2 * c2;
  }
  csq = block_sum_bcast(csq, sred);
  casq = block_sum_bcast(casq, sred);
  // spec partials for graph b live at specp[(b&7) + 8*((b>>3)*64 + t)], t=0..63
  float spec_sum = 0.f;
  if (tid < 64) spec_sum = specp[(b & 7) + 8 * ((b >> 3) * 64 + tid)];
  spec_sum = block_sum_bcast(spec_sum, sred);
  if (tid == 0) {
    float ortho = sqrtf(dsq);
    float cl = sqrtf(csq) * (1.f / 2048.f) * 5.656854249492381f - 1.f;
    float m = 16384.f;
    float spec = -(spec_sum - casq / (2.f * m)) / (2.f * m);
    atomicAdd(loss, (spec + ortho + cl) * (1.f / 16.f));
  }
}

extern "C" void kernel_launch(void* const* d_in, const int* in_sizes, int n_in,
                              void* d_out, int out_size, void* d_ws, size_t ws_size,
                              hipStream_t stream) {
  (void)in_sizes; (void)n_in; (void)out_size; (void)ws_size;
  const float* x   = (const float*)d_in[0];
  const int*   ei  = (const int*)d_in[1];
  const float* gw  = (const float*)d_in[3];
  const float* gb  = (const float*)d_in[4];
  const float* gms = (const float*)d_in[5];
  const float* w1  = (const float*)d_in[6];
  const float* b1  = (const float*)d_in[7];
  const float* w2  = (const float*)d_in[8];
  const float* b2  = (const float*)d_in[9];
  float* out = (float*)d_out;
  float* ws  = (float*)d_ws;

  float* hsc    = ws + OFF_HSC;
  float* part   = ws + OFF_PART;
  float* gsp    = ws + OFF_GSP;
  float* gsp2   = ws + OFF_GSP2;
  float* ssp    = ws + OFF_SSP;
  float* cap    = ws + OFF_CAP;
  float* csp    = ws + OFF_CSP;
  float* specp  = ws + OFF_SWS;            // 1024 floats
  int*   histin = (int*)(ws + OFF_IHIN);
  int*   histout= (int*)(ws + OFF_IHOUT);
  int*   rows   = (int*)(ws + OFF_IROWS);
  int*   esrc   = (int*)(ws + OFF_IESRC);

  float* out0  = out;            // [B,K,HID]
  float* lossp = out + 65536;    // scalar
  float* outs  = out + 65537;    // [B,N,K]

  hipLaunchKernelGGL(k_count, dim3(256), dim3(1024), 0, stream, ei, x, histin, histout, gsp, gsp2);
  hipLaunchKernelGGL(k_prepb, dim3(2176), dim3(256), 0, stream,
                     x, gsp, gsp2, gw, gb, gms, hsc, ei, histin, rows, esrc);
  hipLaunchKernelGGL(k_mm2g, dim3(512), dim3(512), 0, stream,
                     hsc, rows, esrc, w1, b1, w2, b2, histout,
                     outs, ssp, cap, csp, part);
  hipLaunchKernelGGL(k_spec2, dim3(1280), dim3(256), 0, stream,
                     rows, esrc, outs, part, specp, out0, lossp);
  hipLaunchKernelGGL(k_fin2, dim3(16), dim3(256), 0, stream,
                     ssp, csp, cap, specp, lossp);
}